// Round 4
// baseline (238.419 us; speedup 1.0000x reference)
//
#include <hip/hip_runtime.h>
#include <hip/hip_bf16.h>
#include <stdint.h>

typedef __attribute__((ext_vector_type(4))) float f32x4;
typedef __attribute__((ext_vector_type(8))) short short8;

#define B_   32
#define L_   512
#define DE_  512
#define S_   32
#define ED_  128
#define AD_  256
#define HD_  512
#define VOC_ 32000
#define M_   1024

__device__ __forceinline__ unsigned short f2bf(float f){
  union { float f; unsigned int u; } v; v.f = f;
  unsigned int u = v.u;
  unsigned int r = (u + 0x7FFFu + ((u >> 16) & 1u)) >> 16;  // RNE
  return (unsigned short)r;
}

__device__ __forceinline__ float bf2f(unsigned short u){
  union { unsigned int u; float f; } v; v.u = ((unsigned int)u) << 16;
  return v.f;
}

__device__ __forceinline__ float tanh_fast(float x){
  float t = __expf(2.0f * x);
  return (t - 1.0f) * __builtin_amdgcn_rcpf(t + 1.0f);
}

__device__ __forceinline__ void gl_lds16(const void* g, void* l){
  __builtin_amdgcn_global_load_lds(
      (const __attribute__((address_space(1))) unsigned int*)g,
      (__attribute__((address_space(3))) unsigned int*)l, 16, 0, 0);
}

// ---------------- generic f32 -> bf16 (contiguous) ----------------
extern "C" __global__ void __launch_bounds__(256)
k_cvt(const float* __restrict__ src, unsigned short* __restrict__ dst, int n4){
  int stride = gridDim.x * 256;
  for (int i = blockIdx.x * 256 + threadIdx.x; i < n4; i += stride){
    f32x4 v = ((const f32x4*)src)[i];
    ushort4 o;
    o.x = f2bf(v[0]); o.y = f2bf(v[1]); o.z = f2bf(v[2]); o.w = f2bf(v[3]);
    ((ushort4*)dst)[i] = o;
  }
}

// ---------------- dec_query [32][256] f32 and hidden [32][512] bf16 ----------------
extern "C" __global__ void __launch_bounds__(256)
k_small(const float* __restrict__ pos, const float* __restrict__ dW, const float* __restrict__ db,
        const float* __restrict__ hW, const float* __restrict__ hb,
        float* __restrict__ dq, unsigned short* __restrict__ hbf){
  int t = blockIdx.x * 256 + threadIdx.x;
  if (t < S_ * AD_){
    int s = t >> 8, a = t & 255;
    const float* p = pos + s * ED_;
    const float* wrow = dW + a * ED_;
    float acc = db[a];
    #pragma unroll 4
    for (int e = 0; e < ED_; ++e) acc += p[e] * wrow[e];
    dq[t] = acc;
  } else if (t < S_ * AD_ + S_ * HD_){
    int u = t - S_ * AD_;
    int s = u >> 9, h = u & 511;
    const float* p = pos + s * ED_;
    const float* wrow = hW + h * ED_;
    float acc = hb[h];
    #pragma unroll 4
    for (int e = 0; e < ED_; ++e) acc += p[e] * wrow[e];
    hbf[u] = f2bf(acc);
  }
}

// ---------------- enc_proj GEMM: [16384x512]bf16 @ [256x512]bf16^T -> bf16 + bias ----------
extern "C" __global__ void __launch_bounds__(256)
k_gemm_encp(const unsigned short* __restrict__ A, const unsigned short* __restrict__ Bt,
            const float* __restrict__ bias, unsigned short* __restrict__ C){
  __shared__ unsigned short As[128 * 32];
  __shared__ unsigned short Bs[128 * 32];
  int bm = blockIdx.x >> 1, bn = blockIdx.x & 1;
  int tid = threadIdx.x, wid = tid >> 6, lane = tid & 63;
  int fr = lane & 15, fq = lane >> 4;
  int wm = wid >> 1, wn = wid & 1;
  f32x4 acc[4][4];
  #pragma unroll
  for (int i = 0; i < 4; ++i)
    #pragma unroll
    for (int j = 0; j < 4; ++j) acc[i][j] = (f32x4)0.0f;

  for (int k0 = 0; k0 < 512; k0 += 32){
    __syncthreads();
    #pragma unroll
    for (int i = 0; i < 2; ++i){
      int seg = wid * 2 + i;
      int row = seg * 16 + (lane >> 2);
      int col = (lane & 3) * 8;
      gl_lds16(A  + (size_t)(bm * 128 + row) * 512 + k0 + col, &As[seg * 512]);
      gl_lds16(Bt + (size_t)(bn * 128 + row) * 512 + k0 + col, &Bs[seg * 512]);
    }
    __syncthreads();
    short8 a[4], b[4];
    #pragma unroll
    for (int mf = 0; mf < 4; ++mf) a[mf] = *(const short8*)&As[(wm * 64 + mf * 16 + fr) * 32 + fq * 8];
    #pragma unroll
    for (int nf = 0; nf < 4; ++nf) b[nf] = *(const short8*)&Bs[(wn * 64 + nf * 16 + fr) * 32 + fq * 8];
    #pragma unroll
    for (int mf = 0; mf < 4; ++mf)
      #pragma unroll
      for (int nf = 0; nf < 4; ++nf)
        acc[mf][nf] = __builtin_amdgcn_mfma_f32_16x16x32_bf16(a[mf], b[nf], acc[mf][nf], 0, 0, 0);
  }
  #pragma unroll
  for (int mf = 0; mf < 4; ++mf){
    int row = bm * 128 + wm * 64 + mf * 16 + fq * 4;
    #pragma unroll
    for (int nf = 0; nf < 4; ++nf){
      int col = bn * 128 + wn * 64 + nf * 16 + fr;
      float bv = bias[col];
      #pragma unroll
      for (int j = 0; j < 4; ++j)
        C[(size_t)(row + j) * 256 + col] = f2bf(acc[mf][nf][j] + bv);
    }
  }
}

// ---------------- attention scores + softmax -> weights [B][S][L] f32 ----------------
extern "C" __global__ void __launch_bounds__(256)
k_attn(const unsigned short* __restrict__ encp, const float* __restrict__ dq,
       const float* __restrict__ vW, float* __restrict__ wgt){
  int idx = blockIdx.x;
  int wg = (idx & 7) * 128 + (idx >> 3);   // bijective: 1024 % 8 == 0
  int b = wg >> 5, s = wg & 31;
  int tid = threadIdx.x, wid = tid >> 6, lane = tid & 63;
  int half = lane >> 5, a0 = (lane & 31) * 8;
  __shared__ float sc[512];
  __shared__ float redm[4], reds[4];
  f32x4 dqa = *(const f32x4*)&dq[s * AD_ + a0];
  f32x4 dqb = *(const f32x4*)&dq[s * AD_ + a0 + 4];
  f32x4 va  = *(const f32x4*)&vW[a0];
  f32x4 vb  = *(const f32x4*)&vW[a0 + 4];
  for (int it = 0; it < 64; ++it){
    int l = wid * 128 + it * 2 + half;
    short8 e8 = *(const short8*)&encp[((size_t)(b * 512 + l)) * 256 + a0];
    float p = 0.0f;
    #pragma unroll
    for (int j = 0; j < 4; ++j) p += tanh_fast(bf2f((unsigned short)e8[j]) + dqa[j]) * va[j];
    #pragma unroll
    for (int j = 0; j < 4; ++j) p += tanh_fast(bf2f((unsigned short)e8[4 + j]) + dqb[j]) * vb[j];
    #pragma unroll
    for (int off = 16; off >= 1; off >>= 1) p += __shfl_xor(p, off);
    if ((lane & 31) == 0) sc[l] = p;
  }
  __syncthreads();
  float s0 = sc[tid], s1 = sc[tid + 256];
  float m = fmaxf(s0, s1);
  #pragma unroll
  for (int off = 32; off >= 1; off >>= 1) m = fmaxf(m, __shfl_xor(m, off));
  if (lane == 0) redm[wid] = m;
  __syncthreads();
  m = fmaxf(fmaxf(redm[0], redm[1]), fmaxf(redm[2], redm[3]));
  float e0 = __expf(s0 - m), e1 = __expf(s1 - m);
  float sum = e0 + e1;
  #pragma unroll
  for (int off = 32; off >= 1; off >>= 1) sum += __shfl_xor(sum, off);
  if (lane == 0) reds[wid] = sum;
  __syncthreads();
  float tot = reds[0] + reds[1] + reds[2] + reds[3];
  float inv = __builtin_amdgcn_rcpf(tot);
  size_t base = (size_t)(b * 32 + s) * 512;
  wgt[base + tid] = e0 * inv;
  wgt[base + tid + 256] = e1 * inv;
}

// ---------------- context: ctx[b*32+s][d] = sum_l w[b,s,l] * enc_bf[b,l,d] -> bf16 ----------
extern "C" __global__ void __launch_bounds__(256)
k_ctx(const unsigned short* __restrict__ encb, const float* __restrict__ wgt,
      unsigned short* __restrict__ ctx){
  int b = blockIdx.x >> 4, dt = blockIdx.x & 15;
  int tid = threadIdx.x;
  __shared__ float wl[32 * 512];
  #pragma unroll 8
  for (int i = 0; i < 64; ++i)
    wl[i * 256 + tid] = wgt[(size_t)b * 16384 + i * 256 + tid];
  __syncthreads();
  int d = dt * 32 + (tid & 31);
  int grp = tid >> 5;
  float acc0 = 0, acc1 = 0, acc2 = 0, acc3 = 0;
  const unsigned short* ebase = encb + (size_t)b * 262144 + d;   // 512*512
  const float* w0 = &wl[(grp * 4 + 0) * 512];
  const float* w1 = &wl[(grp * 4 + 1) * 512];
  const float* w2 = &wl[(grp * 4 + 2) * 512];
  const float* w3 = &wl[(grp * 4 + 3) * 512];
  #pragma unroll 8
  for (int l = 0; l < 512; ++l){
    float e = bf2f(ebase[(size_t)l * 512]);
    acc0 += w0[l] * e; acc1 += w1[l] * e; acc2 += w2[l] * e; acc3 += w3[l] * e;
  }
  size_t obase = (size_t)(b * 32 + grp * 4) * 512 + d;
  ctx[obase]        = f2bf(acc0);
  ctx[obase + 512]  = f2bf(acc1);
  ctx[obase + 1024] = f2bf(acc2);
  ctx[obase + 1536] = f2bf(acc3);
}

// ---------------- fused: Wc_bf convert (cols 512:1024) + logh (cols 0:512) ----------------
extern "C" __global__ void __launch_bounds__(256)
k_wprep(const float* __restrict__ fcW, const unsigned short* __restrict__ hbf,
        const float* __restrict__ fcb, unsigned short* __restrict__ Wc,
        float* __restrict__ logh){
  int bn = blockIdx.x;                       // 500 blocks x 64 rows of fcW
  int tid = threadIdx.x, wid = tid >> 6, lane = tid & 63;
  int fr = lane & 15, fq = lane >> 4;
  // part 1: convert upper half of 64 rows
  #pragma unroll 8
  for (int i = 0; i < 32; ++i){
    int idx = i * 256 + tid;                 // 8192 f32x4 = 64 rows x 512 cols
    int row = idx >> 7, c4 = idx & 127;
    f32x4 v = *(const f32x4*)&fcW[(size_t)(bn * 64 + row) * 1024 + 512 + c4 * 4];
    ushort4 o;
    o.x = f2bf(v[0]); o.y = f2bf(v[1]); o.z = f2bf(v[2]); o.w = f2bf(v[3]);
    *(ushort4*)&Wc[(size_t)(bn * 64 + row) * 512 + c4 * 4] = o;
  }
  // part 2: logh for these 64 cols (LDS-free, bf16 MFMA vs hbf)
  int col = bn * 64 + wid * 16 + fr;
  const float* brow = fcW + (size_t)col * 1024;
  f32x4 acc0 = (f32x4)0.0f, acc1 = (f32x4)0.0f;
  #pragma unroll 4
  for (int k0 = 0; k0 < 512; k0 += 32){
    int ko = k0 + fq * 8;
    f32x4 b0 = *(const f32x4*)(brow + ko);
    f32x4 b1 = *(const f32x4*)(brow + ko + 4);
    short8 bfr;
    bfr[0] = (short)f2bf(b0[0]); bfr[1] = (short)f2bf(b0[1]);
    bfr[2] = (short)f2bf(b0[2]); bfr[3] = (short)f2bf(b0[3]);
    bfr[4] = (short)f2bf(b1[0]); bfr[5] = (short)f2bf(b1[1]);
    bfr[6] = (short)f2bf(b1[2]); bfr[7] = (short)f2bf(b1[3]);
    short8 a0 = *(const short8*)&hbf[(size_t)fr * 512 + ko];
    short8 a1 = *(const short8*)&hbf[(size_t)(16 + fr) * 512 + ko];
    acc0 = __builtin_amdgcn_mfma_f32_16x16x32_bf16(a0, bfr, acc0, 0, 0, 0);
    acc1 = __builtin_amdgcn_mfma_f32_16x16x32_bf16(a1, bfr, acc1, 0, 0, 0);
  }
  float bv = fcb[col];
  #pragma unroll
  for (int j = 0; j < 4; ++j){
    logh[(size_t)(fq * 4 + j) * VOC_ + col]      = acc0[j] + bv;
    logh[(size_t)(16 + fq * 4 + j) * VOC_ + col] = acc1[j] + bv;
  }
}

// ---------------- main GEMM (256x256 tile, 2-deep counted-vmcnt pipeline, XOR-swizzled LDS):
//   out[m][v] = ctx[m] . Wc[v] + logh[m&31][v]
extern "C" __global__ void __launch_bounds__(512, 1)
k_gemm_main(const unsigned short* __restrict__ Abf, const unsigned short* __restrict__ Wc,
            const float* __restrict__ logh, float* __restrict__ out){
  __shared__ unsigned short As[2][256 * 32];
  __shared__ unsigned short Bs[2][256 * 32];
  // 500 blocks; bijective XCD swizzle (m204: q=62, r=4); bm inner.
  int orig = blockIdx.x;
  int xcd = orig & 7, j = orig >> 3;
  int wgid = (xcd < 4 ? xcd * 63 : 252 + (xcd - 4) * 62) + j;
  int bm = wgid & 3, bn = wgid >> 2;        // bm<4, bn<125
  int tid = threadIdx.x, wid = tid >> 6, lane = tid & 63;
  int fr = lane & 15, fq = lane >> 4;
  int wm = wid >> 2, wn = wid & 3;          // 2 x 4 waves; wave tile 128x64
  int abase = bm * 256, bbase = bn * 256;
  // staging: lane l writes LDS byte l*16 (linear, HW-fixed). Row r=l>>2, slot s=l&3.
  // XOR-swizzle p(r)=(r>>1)&3: slot s holds col-group g = s ^ p(r); pre-swizzle the
  // GLOBAL source col so the linear write lands swizzled (guide §5 T2 / m173).
  int srow = lane >> 2;
  int scol = ((lane & 3) ^ ((lane >> 3) & 3)) * 8;
  int c0 = wid * 2;
  const unsigned short* aS0 = Abf + (size_t)(abase + c0 * 16 + srow) * 512 + scol;
  const unsigned short* aS1 = aS0 + (size_t)16 * 512;
  const unsigned short* bS0 = Wc  + (size_t)(bbase + c0 * 16 + srow) * 512 + scol;
  const unsigned short* bS1 = bS0 + (size_t)16 * 512;
  // read side: slot to read for col-group fq at row R is fq ^ p(R); with R = base16 + fr,
  // p(R) = (fr>>1)&3 -> per-thread constant.
  int swzfq = (fq ^ ((fr >> 1) & 3)) * 8;

  f32x4 acc[8][4];
  #pragma unroll
  for (int i = 0; i < 8; ++i)
    #pragma unroll
    for (int jj = 0; jj < 4; ++jj) acc[i][jj] = (f32x4)0.0f;

#define STAGE_MAIN(buf, kk) do { \
    gl_lds16(aS0 + (kk), &As[buf][c0 * 512]); \
    gl_lds16(aS1 + (kk), &As[buf][c0 * 512 + 512]); \
    gl_lds16(bS0 + (kk), &Bs[buf][c0 * 512]); \
    gl_lds16(bS1 + (kk), &Bs[buf][c0 * 512 + 512]); \
  } while (0)

  // prologue: tiles 0 and 1 in flight
  STAGE_MAIN(0, 0);
  STAGE_MAIN(1, 32);
  asm volatile("s_waitcnt vmcnt(4)" ::: "memory");   // tile 0 landed (per-wave)
  __builtin_amdgcn_s_barrier();                      // landed for ALL waves
  __builtin_amdgcn_sched_barrier(0);

  int cur = 0;
  for (int t = 0; t < 16; ++t){
    short8 a[8], b[4];
    #pragma unroll
    for (int mf = 0; mf < 8; ++mf)
      a[mf] = *(const short8*)&As[cur][(wm * 128 + mf * 16 + fr) * 32 + swzfq];
    #pragma unroll
    for (int nf = 0; nf < 4; ++nf)
      b[nf] = *(const short8*)&Bs[cur][(wn * 64 + nf * 16 + fr) * 32 + swzfq];
    #pragma unroll
    for (int mf = 0; mf < 8; ++mf)
      #pragma unroll
      for (int nf = 0; nf < 4; ++nf)
        acc[mf][nf] = __builtin_amdgcn_mfma_f32_16x16x32_bf16(a[mf], b[nf], acc[mf][nf], 0, 0, 0);
    __builtin_amdgcn_s_barrier();                    // all waves done reading buf[cur]
    __builtin_amdgcn_sched_barrier(0);
    if (t < 14){
      STAGE_MAIN(cur, (size_t)(t + 2) * 32);         // refill buf just freed
      asm volatile("s_waitcnt vmcnt(4)" ::: "memory"); // tile t+1 (oldest 4) landed
    } else if (t == 14){
      asm volatile("s_waitcnt vmcnt(0)" ::: "memory"); // tile 15 landed
    }
    if (t < 15){
      __builtin_amdgcn_s_barrier();                  // landed for ALL waves
      __builtin_amdgcn_sched_barrier(0);
    }
    cur ^= 1;
  }
#undef STAGE_MAIN

  #pragma unroll
  for (int mf = 0; mf < 8; ++mf){
    int rowb = bm * 256 + wm * 128 + mf * 16 + fq * 4;
    #pragma unroll
    for (int nf = 0; nf < 4; ++nf){
      int col = bn * 256 + wn * 64 + nf * 16 + fr;
      #pragma unroll
      for (int jj = 0; jj < 4; ++jj){
        int r = rowb + jj;
        out[(size_t)r * VOC_ + col] = acc[mf][nf][jj] + logh[(size_t)(r & 31) * VOC_ + col];
      }
    }
  }
}

extern "C" void kernel_launch(void* const* d_in, const int* in_sizes, int n_in,
                              void* d_out, int out_size, void* d_ws, size_t ws_size,
                              hipStream_t stream){
  const float* enc = (const float*)d_in[0];
  // d_in[1] = target_seq (unused: only its shape matters in the reference)
  const float* pos = (const float*)d_in[2];
  const float* dW  = (const float*)d_in[3];
  const float* db  = (const float*)d_in[4];
  const float* eW  = (const float*)d_in[5];
  const float* eb  = (const float*)d_in[6];
  const float* vW  = (const float*)d_in[7];
  // d_in[8] = attn_score_b: constant over l, cancels exactly in softmax
  const float* hW  = (const float*)d_in[9];
  const float* hb  = (const float*)d_in[10];
  const float* fcW = (const float*)d_in[11];
  const float* fcb = (const float*)d_in[12];
  float* out = (float*)d_out;

  char* w = (char*)d_ws;
  unsigned short* Wc_bf   = (unsigned short*)(w);               // 32,768,000 B
  unsigned short* enc_bf  = (unsigned short*)(w + 32768000);    // 16,777,216 B
  unsigned short* encp_bf = (unsigned short*)(w + 49545216);    //  8,388,608 B
  unsigned short* ctx     = (unsigned short*)(w + 57933824);    //  1,048,576 B
  float*          logh    = (float*)(w + 58982400);             //  4,096,000 B
  float*          dq      = (float*)(w + 63078400);             //     32,768 B
  unsigned short* hbf     = (unsigned short*)(w + 63111168);    //     32,768 B
  unsigned short* encW_bf = (unsigned short*)(w + 63143936);    //    262,144 B
  float*          wgt     = (float*)(w + 63406080);             //  2,097,152 B (total ~65.5 MB)

  k_cvt<<<dim3(2048), dim3(256), 0, stream>>>(enc, enc_bf, 8388608 / 4);
  k_cvt<<<dim3(128), dim3(256), 0, stream>>>(eW, encW_bf, 131072 / 4);
  k_small<<<dim3(96), dim3(256), 0, stream>>>(pos, dW, db, hW, hb, dq, hbf);
  k_gemm_encp<<<dim3(256), dim3(256), 0, stream>>>(enc_bf, encW_bf, eb, encp_bf);
  k_attn<<<dim3(1024), dim3(256), 0, stream>>>(encp_bf, dq, vW, wgt);
  k_ctx<<<dim3(512), dim3(256), 0, stream>>>(enc_bf, wgt, ctx);
  k_wprep<<<dim3(500), dim3(256), 0, stream>>>(fcW, hbf, fcb, Wc_bf, logh);
  k_gemm_main<<<dim3(500), dim3(512), 0, stream>>>(ctx, Wc_bf, logh, out);
}

// Round 5
// 221.230 us; speedup vs baseline: 1.0777x; 1.0777x over previous
//
#include <hip/hip_runtime.h>
#include <hip/hip_bf16.h>
#include <stdint.h>

typedef __attribute__((ext_vector_type(4))) float f32x4;
typedef __attribute__((ext_vector_type(8))) short short8;

#define B_   32
#define L_   512
#define DE_  512
#define S_   32
#define ED_  128
#define AD_  256
#define HD_  512
#define VOC_ 32000
#define M_   1024

__device__ __forceinline__ unsigned short f2bf(float f){
  union { float f; unsigned int u; } v; v.f = f;
  unsigned int u = v.u;
  unsigned int r = (u + 0x7FFFu + ((u >> 16) & 1u)) >> 16;  // RNE
  return (unsigned short)r;
}

__device__ __forceinline__ float bf2f(unsigned short u){
  union { unsigned int u; float f; } v; v.u = ((unsigned int)u) << 16;
  return v.f;
}

__device__ __forceinline__ float tanh_fast(float x){
  float t = __expf(2.0f * x);
  return (t - 1.0f) * __builtin_amdgcn_rcpf(t + 1.0f);
}

__device__ __forceinline__ void gl_lds16(const void* g, void* l){
  __builtin_amdgcn_global_load_lds(
      (const __attribute__((address_space(1))) unsigned int*)g,
      (__attribute__((address_space(3))) unsigned int*)l, 16, 0, 0);
}

// ---------------- generic f32 -> bf16 (contiguous) ----------------
extern "C" __global__ void __launch_bounds__(256)
k_cvt(const float* __restrict__ src, unsigned short* __restrict__ dst, int n4){
  int stride = gridDim.x * 256;
  for (int i = blockIdx.x * 256 + threadIdx.x; i < n4; i += stride){
    f32x4 v = ((const f32x4*)src)[i];
    ushort4 o;
    o.x = f2bf(v[0]); o.y = f2bf(v[1]); o.z = f2bf(v[2]); o.w = f2bf(v[3]);
    ((ushort4*)dst)[i] = o;
  }
}

// ---------------- dec_query [32][256] f32 and hidden [32][512] bf16 ----------------
extern "C" __global__ void __launch_bounds__(256)
k_small(const float* __restrict__ pos, const float* __restrict__ dW, const float* __restrict__ db,
        const float* __restrict__ hW, const float* __restrict__ hb,
        float* __restrict__ dq, unsigned short* __restrict__ hbf){
  int t = blockIdx.x * 256 + threadIdx.x;
  if (t < S_ * AD_){
    int s = t >> 8, a = t & 255;
    const float* p = pos + s * ED_;
    const float* wrow = dW + a * ED_;
    float acc = db[a];
    #pragma unroll 4
    for (int e = 0; e < ED_; ++e) acc += p[e] * wrow[e];
    dq[t] = acc;
  } else if (t < S_ * AD_ + S_ * HD_){
    int u = t - S_ * AD_;
    int s = u >> 9, h = u & 511;
    const float* p = pos + s * ED_;
    const float* wrow = hW + h * ED_;
    float acc = hb[h];
    #pragma unroll 4
    for (int e = 0; e < ED_; ++e) acc += p[e] * wrow[e];
    hbf[u] = f2bf(acc);
  }
}

// ---------------- enc_proj GEMM: [16384x512]bf16 @ [256x512]bf16^T -> bf16 + bias ----------
extern "C" __global__ void __launch_bounds__(256)
k_gemm_encp(const unsigned short* __restrict__ A, const unsigned short* __restrict__ Bt,
            const float* __restrict__ bias, unsigned short* __restrict__ C){
  __shared__ unsigned short As[128 * 32];
  __shared__ unsigned short Bs[128 * 32];
  int bm = blockIdx.x >> 1, bn = blockIdx.x & 1;
  int tid = threadIdx.x, wid = tid >> 6, lane = tid & 63;
  int fr = lane & 15, fq = lane >> 4;
  int wm = wid >> 1, wn = wid & 1;
  f32x4 acc[4][4];
  #pragma unroll
  for (int i = 0; i < 4; ++i)
    #pragma unroll
    for (int j = 0; j < 4; ++j) acc[i][j] = (f32x4)0.0f;

  for (int k0 = 0; k0 < 512; k0 += 32){
    __syncthreads();
    #pragma unroll
    for (int i = 0; i < 2; ++i){
      int seg = wid * 2 + i;
      int row = seg * 16 + (lane >> 2);
      int col = (lane & 3) * 8;
      gl_lds16(A  + (size_t)(bm * 128 + row) * 512 + k0 + col, &As[seg * 512]);
      gl_lds16(Bt + (size_t)(bn * 128 + row) * 512 + k0 + col, &Bs[seg * 512]);
    }
    __syncthreads();
    short8 a[4], b[4];
    #pragma unroll
    for (int mf = 0; mf < 4; ++mf) a[mf] = *(const short8*)&As[(wm * 64 + mf * 16 + fr) * 32 + fq * 8];
    #pragma unroll
    for (int nf = 0; nf < 4; ++nf) b[nf] = *(const short8*)&Bs[(wn * 64 + nf * 16 + fr) * 32 + fq * 8];
    #pragma unroll
    for (int mf = 0; mf < 4; ++mf)
      #pragma unroll
      for (int nf = 0; nf < 4; ++nf)
        acc[mf][nf] = __builtin_amdgcn_mfma_f32_16x16x32_bf16(a[mf], b[nf], acc[mf][nf], 0, 0, 0);
  }
  #pragma unroll
  for (int mf = 0; mf < 4; ++mf){
    int row = bm * 128 + wm * 64 + mf * 16 + fq * 4;
    #pragma unroll
    for (int nf = 0; nf < 4; ++nf){
      int col = bn * 128 + wn * 64 + nf * 16 + fr;
      float bv = bias[col];
      #pragma unroll
      for (int j = 0; j < 4; ++j)
        C[(size_t)(row + j) * 256 + col] = f2bf(acc[mf][nf][j] + bv);
    }
  }
}

// ---------------- attention scores + softmax -> weights [B][S][L] f32 ----------------
extern "C" __global__ void __launch_bounds__(256)
k_attn(const unsigned short* __restrict__ encp, const float* __restrict__ dq,
       const float* __restrict__ vW, float* __restrict__ wgt){
  int idx = blockIdx.x;
  int wg = (idx & 7) * 128 + (idx >> 3);   // bijective: 1024 % 8 == 0
  int b = wg >> 5, s = wg & 31;
  int tid = threadIdx.x, wid = tid >> 6, lane = tid & 63;
  int half = lane >> 5, a0 = (lane & 31) * 8;
  __shared__ float sc[512];
  __shared__ float redm[4], reds[4];
  f32x4 dqa = *(const f32x4*)&dq[s * AD_ + a0];
  f32x4 dqb = *(const f32x4*)&dq[s * AD_ + a0 + 4];
  f32x4 va  = *(const f32x4*)&vW[a0];
  f32x4 vb  = *(const f32x4*)&vW[a0 + 4];
  for (int it = 0; it < 64; ++it){
    int l = wid * 128 + it * 2 + half;
    short8 e8 = *(const short8*)&encp[((size_t)(b * 512 + l)) * 256 + a0];
    float p = 0.0f;
    #pragma unroll
    for (int j = 0; j < 4; ++j) p += tanh_fast(bf2f((unsigned short)e8[j]) + dqa[j]) * va[j];
    #pragma unroll
    for (int j = 0; j < 4; ++j) p += tanh_fast(bf2f((unsigned short)e8[4 + j]) + dqb[j]) * vb[j];
    #pragma unroll
    for (int off = 16; off >= 1; off >>= 1) p += __shfl_xor(p, off);
    if ((lane & 31) == 0) sc[l] = p;
  }
  __syncthreads();
  float s0 = sc[tid], s1 = sc[tid + 256];
  float m = fmaxf(s0, s1);
  #pragma unroll
  for (int off = 32; off >= 1; off >>= 1) m = fmaxf(m, __shfl_xor(m, off));
  if (lane == 0) redm[wid] = m;
  __syncthreads();
  m = fmaxf(fmaxf(redm[0], redm[1]), fmaxf(redm[2], redm[3]));
  float e0 = __expf(s0 - m), e1 = __expf(s1 - m);
  float sum = e0 + e1;
  #pragma unroll
  for (int off = 32; off >= 1; off >>= 1) sum += __shfl_xor(sum, off);
  if (lane == 0) reds[wid] = sum;
  __syncthreads();
  float tot = reds[0] + reds[1] + reds[2] + reds[3];
  float inv = __builtin_amdgcn_rcpf(tot);
  size_t base = (size_t)(b * 32 + s) * 512;
  wgt[base + tid] = e0 * inv;
  wgt[base + tid + 256] = e1 * inv;
}

// ---------------- context: ctx[b*32+s][d] = sum_l w[b,s,l] * enc_bf[b,l,d] -> bf16 ----------
extern "C" __global__ void __launch_bounds__(256)
k_ctx(const unsigned short* __restrict__ encb, const float* __restrict__ wgt,
      unsigned short* __restrict__ ctx){
  int b = blockIdx.x >> 4, dt = blockIdx.x & 15;
  int tid = threadIdx.x;
  __shared__ float wl[32 * 512];
  #pragma unroll 8
  for (int i = 0; i < 64; ++i)
    wl[i * 256 + tid] = wgt[(size_t)b * 16384 + i * 256 + tid];
  __syncthreads();
  int d = dt * 32 + (tid & 31);
  int grp = tid >> 5;
  float acc0 = 0, acc1 = 0, acc2 = 0, acc3 = 0;
  const unsigned short* ebase = encb + (size_t)b * 262144 + d;   // 512*512
  const float* w0 = &wl[(grp * 4 + 0) * 512];
  const float* w1 = &wl[(grp * 4 + 1) * 512];
  const float* w2 = &wl[(grp * 4 + 2) * 512];
  const float* w3 = &wl[(grp * 4 + 3) * 512];
  #pragma unroll 8
  for (int l = 0; l < 512; ++l){
    float e = bf2f(ebase[(size_t)l * 512]);
    acc0 += w0[l] * e; acc1 += w1[l] * e; acc2 += w2[l] * e; acc3 += w3[l] * e;
  }
  size_t obase = (size_t)(b * 32 + grp * 4) * 512 + d;
  ctx[obase]        = f2bf(acc0);
  ctx[obase + 512]  = f2bf(acc1);
  ctx[obase + 1024] = f2bf(acc2);
  ctx[obase + 1536] = f2bf(acc3);
}

// ---------------- fused: Wc_bf convert (cols 512:1024) + logh (cols 0:512) ----------------
extern "C" __global__ void __launch_bounds__(256)
k_wprep(const float* __restrict__ fcW, const unsigned short* __restrict__ hbf,
        const float* __restrict__ fcb, unsigned short* __restrict__ Wc,
        float* __restrict__ logh){
  int bn = blockIdx.x;                       // 500 blocks x 64 rows of fcW
  int tid = threadIdx.x, wid = tid >> 6, lane = tid & 63;
  int fr = lane & 15, fq = lane >> 4;
  // part 1: convert upper half of 64 rows
  #pragma unroll 8
  for (int i = 0; i < 32; ++i){
    int idx = i * 256 + tid;                 // 8192 f32x4 = 64 rows x 512 cols
    int row = idx >> 7, c4 = idx & 127;
    f32x4 v = *(const f32x4*)&fcW[(size_t)(bn * 64 + row) * 1024 + 512 + c4 * 4];
    ushort4 o;
    o.x = f2bf(v[0]); o.y = f2bf(v[1]); o.z = f2bf(v[2]); o.w = f2bf(v[3]);
    *(ushort4*)&Wc[(size_t)(bn * 64 + row) * 512 + c4 * 4] = o;
  }
  // part 2: logh for these 64 cols (LDS-free, bf16 MFMA vs hbf)
  int col = bn * 64 + wid * 16 + fr;
  const float* brow = fcW + (size_t)col * 1024;
  f32x4 acc0 = (f32x4)0.0f, acc1 = (f32x4)0.0f;
  #pragma unroll 4
  for (int k0 = 0; k0 < 512; k0 += 32){
    int ko = k0 + fq * 8;
    f32x4 b0 = *(const f32x4*)(brow + ko);
    f32x4 b1 = *(const f32x4*)(brow + ko + 4);
    short8 bfr;
    bfr[0] = (short)f2bf(b0[0]); bfr[1] = (short)f2bf(b0[1]);
    bfr[2] = (short)f2bf(b0[2]); bfr[3] = (short)f2bf(b0[3]);
    bfr[4] = (short)f2bf(b1[0]); bfr[5] = (short)f2bf(b1[1]);
    bfr[6] = (short)f2bf(b1[2]); bfr[7] = (short)f2bf(b1[3]);
    short8 a0 = *(const short8*)&hbf[(size_t)fr * 512 + ko];
    short8 a1 = *(const short8*)&hbf[(size_t)(16 + fr) * 512 + ko];
    acc0 = __builtin_amdgcn_mfma_f32_16x16x32_bf16(a0, bfr, acc0, 0, 0, 0);
    acc1 = __builtin_amdgcn_mfma_f32_16x16x32_bf16(a1, bfr, acc1, 0, 0, 0);
  }
  float bv = fcb[col];
  #pragma unroll
  for (int j = 0; j < 4; ++j){
    logh[(size_t)(fq * 4 + j) * VOC_ + col]      = acc0[j] + bv;
    logh[(size_t)(16 + fq * 4 + j) * VOC_ + col] = acc1[j] + bv;
  }
}

// ---------------- main GEMM (256x256 tile, 2-phase dbuf, zero-conflict XOR-swizzled LDS):
//   out[m][v] = ctx[m] . Wc[v] + logh[m&31][v]
extern "C" __global__ void __launch_bounds__(512, 2)
k_gemm_main(const unsigned short* __restrict__ Abf, const unsigned short* __restrict__ Wc,
            const float* __restrict__ logh, float* __restrict__ out){
  __shared__ unsigned short As[2][256 * 32];
  __shared__ unsigned short Bs[2][256 * 32];
  // 500 blocks; bijective XCD swizzle (m204: q=62, r=4); bm inner.
  int orig = blockIdx.x;
  int xcd = orig & 7, j = orig >> 3;
  int wgid = (xcd < 4 ? xcd * 63 : 252 + (xcd - 4) * 62) + j;
  int bm = wgid & 3, bn = wgid >> 2;        // bm<4, bn<125
  int tid = threadIdx.x, wid = tid >> 6, lane = tid & 63;
  int fr = lane & 15, fq = lane >> 4;
  int wm = wid >> 2, wn = wid & 3;          // 2 x 4 waves; wave tile 128x64
  int abase = bm * 256, bbase = bn * 256;
  // staging: lane l writes LDS byte l*16 (linear, HW-fixed). Row r=l>>2, slot s=l&3.
  // XOR-swizzle p(r)=(r>>1)&3: slot s holds col-group g = s ^ p(r); pre-swizzle the
  // GLOBAL source col so the linear write lands swizzled (verified R4: conflicts=0).
  int srow = lane >> 2;
  int scol = ((lane & 3) ^ ((lane >> 3) & 3)) * 8;
  int c0 = wid * 2;
  const unsigned short* aS0 = Abf + (size_t)(abase + c0 * 16 + srow) * 512 + scol;
  const unsigned short* aS1 = aS0 + (size_t)16 * 512;
  const unsigned short* bS0 = Wc  + (size_t)(bbase + c0 * 16 + srow) * 512 + scol;
  const unsigned short* bS1 = bS0 + (size_t)16 * 512;
  // read side: slot for col-group fq at row R=base16+fr is fq ^ ((fr>>1)&3) -> constant.
  int swzfq = (fq ^ ((fr >> 1) & 3)) * 8;

  f32x4 acc[8][4];
  #pragma unroll
  for (int i = 0; i < 8; ++i)
    #pragma unroll
    for (int jj = 0; jj < 4; ++jj) acc[i][jj] = (f32x4)0.0f;

#define STAGE_MAIN(buf, kk) do { \
    gl_lds16(aS0 + (kk), &As[buf][c0 * 512]); \
    gl_lds16(aS1 + (kk), &As[buf][c0 * 512 + 512]); \
    gl_lds16(bS0 + (kk), &Bs[buf][c0 * 512]); \
    gl_lds16(bS1 + (kk), &Bs[buf][c0 * 512 + 512]); \
  } while (0)

  // prologue: stage K-tile 0 into buf 0
  STAGE_MAIN(0, 0);
  __syncthreads();   // drains vmcnt(0) + barrier

  int cur = 0;
  for (int t = 0; t < 16; ++t){
    // stage next K-tile into the other buffer (overlaps with ds_read+MFMA below)
    if (t < 15) STAGE_MAIN(cur ^ 1, (size_t)(t + 1) * 32);
    short8 a[8], b[4];
    #pragma unroll
    for (int mf = 0; mf < 8; ++mf)
      a[mf] = *(const short8*)&As[cur][(wm * 128 + mf * 16 + fr) * 32 + swzfq];
    #pragma unroll
    for (int nf = 0; nf < 4; ++nf)
      b[nf] = *(const short8*)&Bs[cur][(wn * 64 + nf * 16 + fr) * 32 + swzfq];
    #pragma unroll
    for (int mf = 0; mf < 8; ++mf)
      #pragma unroll
      for (int nf = 0; nf < 4; ++nf)
        acc[mf][nf] = __builtin_amdgcn_mfma_f32_16x16x32_bf16(a[mf], b[nf], acc[mf][nf], 0, 0, 0);
    __syncthreads();   // reads of buf[cur] done by all waves; staged buf[cur^1] drained
    cur ^= 1;
  }
#undef STAGE_MAIN

  #pragma unroll
  for (int mf = 0; mf < 8; ++mf){
    int rowb = bm * 256 + wm * 128 + mf * 16 + fq * 4;
    #pragma unroll
    for (int nf = 0; nf < 4; ++nf){
      int col = bn * 256 + wn * 64 + nf * 16 + fr;
      #pragma unroll
      for (int jj = 0; jj < 4; ++jj){
        int r = rowb + jj;
        out[(size_t)r * VOC_ + col] = acc[mf][nf][jj] + logh[(size_t)(r & 31) * VOC_ + col];
      }
    }
  }
}

extern "C" void kernel_launch(void* const* d_in, const int* in_sizes, int n_in,
                              void* d_out, int out_size, void* d_ws, size_t ws_size,
                              hipStream_t stream){
  const float* enc = (const float*)d_in[0];
  // d_in[1] = target_seq (unused: only its shape matters in the reference)
  const float* pos = (const float*)d_in[2];
  const float* dW  = (const float*)d_in[3];
  const float* db  = (const float*)d_in[4];
  const float* eW  = (const float*)d_in[5];
  const float* eb  = (const float*)d_in[6];
  const float* vW  = (const float*)d_in[7];
  // d_in[8] = attn_score_b: constant over l, cancels exactly in softmax
  const float* hW  = (const float*)d_in[9];
  const float* hb  = (const float*)d_in[10];
  const float* fcW = (const float*)d_in[11];
  const float* fcb = (const float*)d_in[12];
  float* out = (float*)d_out;

  char* w = (char*)d_ws;
  unsigned short* Wc_bf   = (unsigned short*)(w);               // 32,768,000 B
  unsigned short* enc_bf  = (unsigned short*)(w + 32768000);    // 16,777,216 B
  unsigned short* encp_bf = (unsigned short*)(w + 49545216);    //  8,388,608 B
  unsigned short* ctx     = (unsigned short*)(w + 57933824);    //  1,048,576 B
  float*          logh    = (float*)(w + 58982400);             //  4,096,000 B
  float*          dq      = (float*)(w + 63078400);             //     32,768 B
  unsigned short* hbf     = (unsigned short*)(w + 63111168);    //     32,768 B
  unsigned short* encW_bf = (unsigned short*)(w + 63143936);    //    262,144 B
  float*          wgt     = (float*)(w + 63406080);             //  2,097,152 B (total ~65.5 MB)

  k_cvt<<<dim3(2048), dim3(256), 0, stream>>>(enc, enc_bf, 8388608 / 4);
  k_cvt<<<dim3(128), dim3(256), 0, stream>>>(eW, encW_bf, 131072 / 4);
  k_small<<<dim3(96), dim3(256), 0, stream>>>(pos, dW, db, hW, hb, dq, hbf);
  k_gemm_encp<<<dim3(256), dim3(256), 0, stream>>>(enc_bf, encW_bf, eb, encp_bf);
  k_attn<<<dim3(1024), dim3(256), 0, stream>>>(encp_bf, dq, vW, wgt);
  k_ctx<<<dim3(512), dim3(256), 0, stream>>>(enc_bf, wgt, ctx);
  k_wprep<<<dim3(500), dim3(256), 0, stream>>>(fcW, hbf, fcb, Wc_bf, logh);
  k_gemm_main<<<dim3(500), dim3(512), 0, stream>>>(ctx, Wc_bf, logh, out);
}

// Round 6
// 210.600 us; speedup vs baseline: 1.1321x; 1.0505x over previous
//
#include <hip/hip_runtime.h>
#include <hip/hip_bf16.h>
#include <stdint.h>

typedef __attribute__((ext_vector_type(4))) float f32x4;
typedef __attribute__((ext_vector_type(8))) short short8;

#define B_   32
#define L_   512
#define DE_  512
#define S_   32
#define ED_  128
#define AD_  256
#define HD_  512
#define VOC_ 32000
#define M_   1024

__device__ __forceinline__ unsigned short f2bf(float f){
  union { float f; unsigned int u; } v; v.f = f;
  unsigned int u = v.u;
  unsigned int r = (u + 0x7FFFu + ((u >> 16) & 1u)) >> 16;  // RNE
  return (unsigned short)r;
}

__device__ __forceinline__ float bf2f(unsigned short u){
  union { unsigned int u; float f; } v; v.u = ((unsigned int)u) << 16;
  return v.f;
}

__device__ __forceinline__ float tanh_fast(float x){
  float t = __expf(2.0f * x);
  return (t - 1.0f) * __builtin_amdgcn_rcpf(t + 1.0f);
}

__device__ __forceinline__ void gl_lds16(const void* g, void* l){
  __builtin_amdgcn_global_load_lds(
      (const __attribute__((address_space(1))) unsigned int*)g,
      (__attribute__((address_space(3))) unsigned int*)l, 16, 0, 0);
}

// ---------------- generic f32 -> bf16 (contiguous) ----------------
extern "C" __global__ void __launch_bounds__(256)
k_cvt(const float* __restrict__ src, unsigned short* __restrict__ dst, int n4){
  int stride = gridDim.x * 256;
  for (int i = blockIdx.x * 256 + threadIdx.x; i < n4; i += stride){
    f32x4 v = ((const f32x4*)src)[i];
    ushort4 o;
    o.x = f2bf(v[0]); o.y = f2bf(v[1]); o.z = f2bf(v[2]); o.w = f2bf(v[3]);
    ((ushort4*)dst)[i] = o;
  }
}

// ---------------- dec_query [32][256] f32 and hidden [32][512] bf16 ----------------
extern "C" __global__ void __launch_bounds__(256)
k_small(const float* __restrict__ pos, const float* __restrict__ dW, const float* __restrict__ db,
        const float* __restrict__ hW, const float* __restrict__ hb,
        float* __restrict__ dq, unsigned short* __restrict__ hbf){
  int t = blockIdx.x * 256 + threadIdx.x;
  if (t < S_ * AD_){
    int s = t >> 8, a = t & 255;
    const float* p = pos + s * ED_;
    const float* wrow = dW + a * ED_;
    float acc = db[a];
    #pragma unroll 4
    for (int e = 0; e < ED_; ++e) acc += p[e] * wrow[e];
    dq[t] = acc;
  } else if (t < S_ * AD_ + S_ * HD_){
    int u = t - S_ * AD_;
    int s = u >> 9, h = u & 511;
    const float* p = pos + s * ED_;
    const float* wrow = hW + h * ED_;
    float acc = hb[h];
    #pragma unroll 4
    for (int e = 0; e < ED_; ++e) acc += p[e] * wrow[e];
    hbf[u] = f2bf(acc);
  }
}

// ---------------- enc_proj GEMM: [16384x512]bf16 @ [256x512]bf16^T -> bf16 + bias ----------
extern "C" __global__ void __launch_bounds__(256)
k_gemm_encp(const unsigned short* __restrict__ A, const unsigned short* __restrict__ Bt,
            const float* __restrict__ bias, unsigned short* __restrict__ C){
  __shared__ unsigned short As[128 * 32];
  __shared__ unsigned short Bs[128 * 32];
  int bm = blockIdx.x >> 1, bn = blockIdx.x & 1;
  int tid = threadIdx.x, wid = tid >> 6, lane = tid & 63;
  int fr = lane & 15, fq = lane >> 4;
  int wm = wid >> 1, wn = wid & 1;
  f32x4 acc[4][4];
  #pragma unroll
  for (int i = 0; i < 4; ++i)
    #pragma unroll
    for (int j = 0; j < 4; ++j) acc[i][j] = (f32x4)0.0f;

  for (int k0 = 0; k0 < 512; k0 += 32){
    __syncthreads();
    #pragma unroll
    for (int i = 0; i < 2; ++i){
      int seg = wid * 2 + i;
      int row = seg * 16 + (lane >> 2);
      int col = (lane & 3) * 8;
      gl_lds16(A  + (size_t)(bm * 128 + row) * 512 + k0 + col, &As[seg * 512]);
      gl_lds16(Bt + (size_t)(bn * 128 + row) * 512 + k0 + col, &Bs[seg * 512]);
    }
    __syncthreads();
    short8 a[4], b[4];
    #pragma unroll
    for (int mf = 0; mf < 4; ++mf) a[mf] = *(const short8*)&As[(wm * 64 + mf * 16 + fr) * 32 + fq * 8];
    #pragma unroll
    for (int nf = 0; nf < 4; ++nf) b[nf] = *(const short8*)&Bs[(wn * 64 + nf * 16 + fr) * 32 + fq * 8];
    #pragma unroll
    for (int mf = 0; mf < 4; ++mf)
      #pragma unroll
      for (int nf = 0; nf < 4; ++nf)
        acc[mf][nf] = __builtin_amdgcn_mfma_f32_16x16x32_bf16(a[mf], b[nf], acc[mf][nf], 0, 0, 0);
  }
  #pragma unroll
  for (int mf = 0; mf < 4; ++mf){
    int row = bm * 128 + wm * 64 + mf * 16 + fq * 4;
    #pragma unroll
    for (int nf = 0; nf < 4; ++nf){
      int col = bn * 128 + wn * 64 + nf * 16 + fr;
      float bv = bias[col];
      #pragma unroll
      for (int j = 0; j < 4; ++j)
        C[(size_t)(row + j) * 256 + col] = f2bf(acc[mf][nf][j] + bv);
    }
  }
}

// ---------------- attention scores + softmax -> weights [B][S][L] f32 ----------------
extern "C" __global__ void __launch_bounds__(256)
k_attn(const unsigned short* __restrict__ encp, const float* __restrict__ dq,
       const float* __restrict__ vW, float* __restrict__ wgt){
  int idx = blockIdx.x;
  int wg = (idx & 7) * 128 + (idx >> 3);   // bijective: 1024 % 8 == 0
  int b = wg >> 5, s = wg & 31;
  int tid = threadIdx.x, wid = tid >> 6, lane = tid & 63;
  int half = lane >> 5, a0 = (lane & 31) * 8;
  __shared__ float sc[512];
  __shared__ float redm[4], reds[4];
  f32x4 dqa = *(const f32x4*)&dq[s * AD_ + a0];
  f32x4 dqb = *(const f32x4*)&dq[s * AD_ + a0 + 4];
  f32x4 va  = *(const f32x4*)&vW[a0];
  f32x4 vb  = *(const f32x4*)&vW[a0 + 4];
  for (int it = 0; it < 64; ++it){
    int l = wid * 128 + it * 2 + half;
    short8 e8 = *(const short8*)&encp[((size_t)(b * 512 + l)) * 256 + a0];
    float p = 0.0f;
    #pragma unroll
    for (int j = 0; j < 4; ++j) p += tanh_fast(bf2f((unsigned short)e8[j]) + dqa[j]) * va[j];
    #pragma unroll
    for (int j = 0; j < 4; ++j) p += tanh_fast(bf2f((unsigned short)e8[4 + j]) + dqb[j]) * vb[j];
    #pragma unroll
    for (int off = 16; off >= 1; off >>= 1) p += __shfl_xor(p, off);
    if ((lane & 31) == 0) sc[l] = p;
  }
  __syncthreads();
  float s0 = sc[tid], s1 = sc[tid + 256];
  float m = fmaxf(s0, s1);
  #pragma unroll
  for (int off = 32; off >= 1; off >>= 1) m = fmaxf(m, __shfl_xor(m, off));
  if (lane == 0) redm[wid] = m;
  __syncthreads();
  m = fmaxf(fmaxf(redm[0], redm[1]), fmaxf(redm[2], redm[3]));
  float e0 = __expf(s0 - m), e1 = __expf(s1 - m);
  float sum = e0 + e1;
  #pragma unroll
  for (int off = 32; off >= 1; off >>= 1) sum += __shfl_xor(sum, off);
  if (lane == 0) reds[wid] = sum;
  __syncthreads();
  float tot = reds[0] + reds[1] + reds[2] + reds[3];
  float inv = __builtin_amdgcn_rcpf(tot);
  size_t base = (size_t)(b * 32 + s) * 512;
  wgt[base + tid] = e0 * inv;
  wgt[base + tid + 256] = e1 * inv;
}

// ---------------- context: ctx[b*32+s][d] = sum_l w[b,s,l] * enc_bf[b,l,d] -> bf16 ----------
extern "C" __global__ void __launch_bounds__(256)
k_ctx(const unsigned short* __restrict__ encb, const float* __restrict__ wgt,
      unsigned short* __restrict__ ctx){
  int b = blockIdx.x >> 4, dt = blockIdx.x & 15;
  int tid = threadIdx.x;
  __shared__ float wl[32 * 512];
  #pragma unroll 8
  for (int i = 0; i < 64; ++i)
    wl[i * 256 + tid] = wgt[(size_t)b * 16384 + i * 256 + tid];
  __syncthreads();
  int d = dt * 32 + (tid & 31);
  int grp = tid >> 5;
  float acc0 = 0, acc1 = 0, acc2 = 0, acc3 = 0;
  const unsigned short* ebase = encb + (size_t)b * 262144 + d;   // 512*512
  const float* w0 = &wl[(grp * 4 + 0) * 512];
  const float* w1 = &wl[(grp * 4 + 1) * 512];
  const float* w2 = &wl[(grp * 4 + 2) * 512];
  const float* w3 = &wl[(grp * 4 + 3) * 512];
  #pragma unroll 8
  for (int l = 0; l < 512; ++l){
    float e = bf2f(ebase[(size_t)l * 512]);
    acc0 += w0[l] * e; acc1 += w1[l] * e; acc2 += w2[l] * e; acc3 += w3[l] * e;
  }
  size_t obase = (size_t)(b * 32 + grp * 4) * 512 + d;
  ctx[obase]        = f2bf(acc0);
  ctx[obase + 512]  = f2bf(acc1);
  ctx[obase + 1024] = f2bf(acc2);
  ctx[obase + 1536] = f2bf(acc3);
}

// ---------------- fused: Wc_bf convert (cols 512:1024) + logh (cols 0:512) ----------------
extern "C" __global__ void __launch_bounds__(256)
k_wprep(const float* __restrict__ fcW, const unsigned short* __restrict__ hbf,
        const float* __restrict__ fcb, unsigned short* __restrict__ Wc,
        float* __restrict__ logh){
  int bn = blockIdx.x;                       // 500 blocks x 64 rows of fcW
  int tid = threadIdx.x, wid = tid >> 6, lane = tid & 63;
  int fr = lane & 15, fq = lane >> 4;
  // part 1: convert upper half of 64 rows
  #pragma unroll 8
  for (int i = 0; i < 32; ++i){
    int idx = i * 256 + tid;                 // 8192 f32x4 = 64 rows x 512 cols
    int row = idx >> 7, c4 = idx & 127;
    f32x4 v = *(const f32x4*)&fcW[(size_t)(bn * 64 + row) * 1024 + 512 + c4 * 4];
    ushort4 o;
    o.x = f2bf(v[0]); o.y = f2bf(v[1]); o.z = f2bf(v[2]); o.w = f2bf(v[3]);
    *(ushort4*)&Wc[(size_t)(bn * 64 + row) * 512 + c4 * 4] = o;
  }
  // part 2: logh for these 64 cols (LDS-free, bf16 MFMA vs hbf)
  int col = bn * 64 + wid * 16 + fr;
  const float* brow = fcW + (size_t)col * 1024;
  f32x4 acc0 = (f32x4)0.0f, acc1 = (f32x4)0.0f;
  #pragma unroll 4
  for (int k0 = 0; k0 < 512; k0 += 32){
    int ko = k0 + fq * 8;
    f32x4 b0 = *(const f32x4*)(brow + ko);
    f32x4 b1 = *(const f32x4*)(brow + ko + 4);
    short8 bfr;
    bfr[0] = (short)f2bf(b0[0]); bfr[1] = (short)f2bf(b0[1]);
    bfr[2] = (short)f2bf(b0[2]); bfr[3] = (short)f2bf(b0[3]);
    bfr[4] = (short)f2bf(b1[0]); bfr[5] = (short)f2bf(b1[1]);
    bfr[6] = (short)f2bf(b1[2]); bfr[7] = (short)f2bf(b1[3]);
    short8 a0 = *(const short8*)&hbf[(size_t)fr * 512 + ko];
    short8 a1 = *(const short8*)&hbf[(size_t)(16 + fr) * 512 + ko];
    acc0 = __builtin_amdgcn_mfma_f32_16x16x32_bf16(a0, bfr, acc0, 0, 0, 0);
    acc1 = __builtin_amdgcn_mfma_f32_16x16x32_bf16(a1, bfr, acc1, 0, 0, 0);
  }
  float bv = fcb[col];
  #pragma unroll
  for (int j = 0; j < 4; ++j){
    logh[(size_t)(fq * 4 + j) * VOC_ + col]      = acc0[j] + bv;
    logh[(size_t)(16 + fq * 4 + j) * VOC_ + col] = acc1[j] + bv;
  }
}

// ---------------- main GEMM (256x256 tile, A-dbuf + B-3buf, counted vmcnt(2), swizzled LDS):
//   out[m][v] = ctx[m] . Wc[v] + logh[m&31][v]
extern "C" __global__ void __launch_bounds__(512, 2)
k_gemm_main(const unsigned short* __restrict__ Abf, const unsigned short* __restrict__ Wc,
            const float* __restrict__ logh, float* __restrict__ out){
  __shared__ unsigned short As[2][256 * 32];   // 32 KB: A double-buffer (ctx, L2-resident)
  __shared__ unsigned short Bs[3][256 * 32];   // 48 KB: B triple-buffer (Wc, HBM-latency)
  // 500 blocks; bijective XCD swizzle (m204: q=62, r=4); bm inner.
  int orig = blockIdx.x;
  int xcd = orig & 7, j = orig >> 3;
  int wgid = (xcd < 4 ? xcd * 63 : 252 + (xcd - 4) * 62) + j;
  int bm = wgid & 3, bn = wgid >> 2;        // bm<4, bn<125
  int tid = threadIdx.x, wid = tid >> 6, lane = tid & 63;
  int fr = lane & 15, fq = lane >> 4;
  int wm = wid >> 2, wn = wid & 3;          // 2 x 4 waves; wave tile 128x64
  int abase = bm * 256, bbase = bn * 256;
  // staging: lane l writes LDS byte l*16 (linear). Row r=l>>2, slot s=l&3.
  // XOR-swizzle p(r)=(r>>1)&3 applied by pre-swizzling the GLOBAL source col
  // (verified R4/R5: SQ_LDS_BANK_CONFLICT = 0).
  int srow = lane >> 2;
  int scol = ((lane & 3) ^ ((lane >> 3) & 3)) * 8;
  int c0 = wid * 2;
  const unsigned short* aS0 = Abf + (size_t)(abase + c0 * 16 + srow) * 512 + scol;
  const unsigned short* aS1 = aS0 + (size_t)16 * 512;
  const unsigned short* bS0 = Wc  + (size_t)(bbase + c0 * 16 + srow) * 512 + scol;
  const unsigned short* bS1 = bS0 + (size_t)16 * 512;
  // read side: slot for col-group fq at row R=base16+fr is fq ^ ((fr>>1)&3) -> constant.
  int swzfq = (fq ^ ((fr >> 1) & 3)) * 8;

  f32x4 acc[8][4];
  #pragma unroll
  for (int i = 0; i < 8; ++i)
    #pragma unroll
    for (int jj = 0; jj < 4; ++jj) acc[i][jj] = (f32x4)0.0f;

#define STAGE_A(buf, kk) do { \
    gl_lds16(aS0 + (kk), &As[buf][c0 * 512]); \
    gl_lds16(aS1 + (kk), &As[buf][c0 * 512 + 512]); \
  } while (0)
#define STAGE_B(buf, kk) do { \
    gl_lds16(bS0 + (kk), &Bs[buf][c0 * 512]); \
    gl_lds16(bS1 + (kk), &Bs[buf][c0 * 512 + 512]); \
  } while (0)

  // prologue: A(0), B(0) needed now; B(1) may stay in flight.
  STAGE_A(0, 0);
  STAGE_B(0, 0);
  STAGE_B(1, 32);
  asm volatile("s_waitcnt vmcnt(2)" ::: "memory");   // A0,B0 landed; B1 flying
  __builtin_amdgcn_s_barrier();
  __builtin_amdgcn_sched_barrier(0);

  #pragma unroll
  for (int t = 0; t < 16; ++t){
    const int ca = t & 1, cb = t % 3;
    short8 a[8], b[4];
    // ---- phase 0: stage A(t+1); compute mf0-3 ----
    if (t < 15) STAGE_A(ca ^ 1, (size_t)(t + 1) * 32);
    #pragma unroll
    for (int nf = 0; nf < 4; ++nf)
      b[nf] = *(const short8*)&Bs[cb][(wn * 64 + nf * 16 + fr) * 32 + swzfq];
    #pragma unroll
    for (int mf = 0; mf < 4; ++mf)
      a[mf] = *(const short8*)&As[ca][(wm * 128 + mf * 16 + fr) * 32 + swzfq];
    __builtin_amdgcn_s_setprio(1);
    #pragma unroll
    for (int mf = 0; mf < 4; ++mf)
      #pragma unroll
      for (int nf = 0; nf < 4; ++nf)
        acc[mf][nf] = __builtin_amdgcn_mfma_f32_16x16x32_bf16(a[mf], b[nf], acc[mf][nf], 0, 0, 0);
    __builtin_amdgcn_s_setprio(0);
    // ---- phase 1: stage B(t+2); compute mf4-7 ----
    if (t < 14) STAGE_B((t + 2) % 3, (size_t)(t + 2) * 32);
    #pragma unroll
    for (int mf = 4; mf < 8; ++mf)
      a[mf] = *(const short8*)&As[ca][(wm * 128 + mf * 16 + fr) * 32 + swzfq];
    __builtin_amdgcn_s_setprio(1);
    #pragma unroll
    for (int mf = 4; mf < 8; ++mf)
      #pragma unroll
      for (int nf = 0; nf < 4; ++nf)
        acc[mf][nf] = __builtin_amdgcn_mfma_f32_16x16x32_bf16(a[mf], b[nf], acc[mf][nf], 0, 0, 0);
    __builtin_amdgcn_s_setprio(0);
    // ---- tile boundary: A(t+1),B(t+1) must be landed; B(t+2) may fly ----
    if (t < 14)      asm volatile("s_waitcnt vmcnt(2)" ::: "memory");
    else if (t == 14) asm volatile("s_waitcnt vmcnt(0)" ::: "memory");
    if (t < 15){
      __builtin_amdgcn_s_barrier();
      __builtin_amdgcn_sched_barrier(0);
    }
  }
#undef STAGE_A
#undef STAGE_B

  #pragma unroll
  for (int mf = 0; mf < 8; ++mf){
    int rowb = bm * 256 + wm * 128 + mf * 16 + fq * 4;
    #pragma unroll
    for (int nf = 0; nf < 4; ++nf){
      int col = bn * 256 + wn * 64 + nf * 16 + fr;
      #pragma unroll
      for (int jj = 0; jj < 4; ++jj){
        int r = rowb + jj;
        out[(size_t)r * VOC_ + col] = acc[mf][nf][jj] + logh[(size_t)(r & 31) * VOC_ + col];
      }
    }
  }
}

extern "C" void kernel_launch(void* const* d_in, const int* in_sizes, int n_in,
                              void* d_out, int out_size, void* d_ws, size_t ws_size,
                              hipStream_t stream){
  const float* enc = (const float*)d_in[0];
  // d_in[1] = target_seq (unused: only its shape matters in the reference)
  const float* pos = (const float*)d_in[2];
  const float* dW  = (const float*)d_in[3];
  const float* db  = (const float*)d_in[4];
  const float* eW  = (const float*)d_in[5];
  const float* eb  = (const float*)d_in[6];
  const float* vW  = (const float*)d_in[7];
  // d_in[8] = attn_score_b: constant over l, cancels exactly in softmax
  const float* hW  = (const float*)d_in[9];
  const float* hb  = (const float*)d_in[10];
  const float* fcW = (const float*)d_in[11];
  const float* fcb = (const float*)d_in[12];
  float* out = (float*)d_out;

  char* w = (char*)d_ws;
  unsigned short* Wc_bf   = (unsigned short*)(w);               // 32,768,000 B
  unsigned short* enc_bf  = (unsigned short*)(w + 32768000);    // 16,777,216 B
  unsigned short* encp_bf = (unsigned short*)(w + 49545216);    //  8,388,608 B
  unsigned short* ctx     = (unsigned short*)(w + 57933824);    //  1,048,576 B
  float*          logh    = (float*)(w + 58982400);             //  4,096,000 B
  float*          dq      = (float*)(w + 63078400);             //     32,768 B
  unsigned short* hbf     = (unsigned short*)(w + 63111168);    //     32,768 B
  unsigned short* encW_bf = (unsigned short*)(w + 63143936);    //    262,144 B
  float*          wgt     = (float*)(w + 63406080);             //  2,097,152 B (total ~65.5 MB)

  k_cvt<<<dim3(2048), dim3(256), 0, stream>>>(enc, enc_bf, 8388608 / 4);
  k_cvt<<<dim3(128), dim3(256), 0, stream>>>(eW, encW_bf, 131072 / 4);
  k_small<<<dim3(96), dim3(256), 0, stream>>>(pos, dW, db, hW, hb, dq, hbf);
  k_gemm_encp<<<dim3(256), dim3(256), 0, stream>>>(enc_bf, encW_bf, eb, encp_bf);
  k_attn<<<dim3(1024), dim3(256), 0, stream>>>(encp_bf, dq, vW, wgt);
  k_ctx<<<dim3(512), dim3(256), 0, stream>>>(enc_bf, wgt, ctx);
  k_wprep<<<dim3(500), dim3(256), 0, stream>>>(fcW, hbf, fcb, Wc_bf, logh);
  k_gemm_main<<<dim3(500), dim3(512), 0, stream>>>(ctx, Wc_bf, logh, out);
}

// Round 7
// 209.294 us; speedup vs baseline: 1.1392x; 1.0062x over previous
//
#include <hip/hip_runtime.h>
#include <hip/hip_bf16.h>
#include <stdint.h>

typedef __attribute__((ext_vector_type(4))) float f32x4;
typedef __attribute__((ext_vector_type(8))) short short8;

#define B_   32
#define L_   512
#define DE_  512
#define S_   32
#define ED_  128
#define AD_  256
#define HD_  512
#define VOC_ 32000
#define M_   1024

__device__ __forceinline__ unsigned short f2bf(float f){
  union { float f; unsigned int u; } v; v.f = f;
  unsigned int u = v.u;
  unsigned int r = (u + 0x7FFFu + ((u >> 16) & 1u)) >> 16;  // RNE
  return (unsigned short)r;
}

__device__ __forceinline__ float bf2f(unsigned short u){
  union { unsigned int u; float f; } v; v.u = ((unsigned int)u) << 16;
  return v.f;
}

__device__ __forceinline__ float tanh_fast(float x){
  float t = __expf(2.0f * x);
  return (t - 1.0f) * __builtin_amdgcn_rcpf(t + 1.0f);
}

__device__ __forceinline__ void gl_lds16(const void* g, void* l){
  __builtin_amdgcn_global_load_lds(
      (const __attribute__((address_space(1))) unsigned int*)g,
      (__attribute__((address_space(3))) unsigned int*)l, 16, 0, 0);
}

// ---------------- fused prologue: enc cvt (8192 blk) + eW cvt (128 blk) + small (96 blk) ----
extern "C" __global__ void __launch_bounds__(256)
k_prep(const float* __restrict__ enc, unsigned short* __restrict__ enc_bf,
       const float* __restrict__ eW, unsigned short* __restrict__ encW_bf,
       const float* __restrict__ pos,
       const float* __restrict__ dW, const float* __restrict__ db,
       const float* __restrict__ hW, const float* __restrict__ hb,
       float* __restrict__ dq, unsigned short* __restrict__ hbf){
  int blk = blockIdx.x, tid = threadIdx.x;
  if (blk < 8192){                       // enc: 2,097,152 f32x4, one per thread
    int i = blk * 256 + tid;
    f32x4 v = ((const f32x4*)enc)[i];
    ushort4 o;
    o.x = f2bf(v[0]); o.y = f2bf(v[1]); o.z = f2bf(v[2]); o.w = f2bf(v[3]);
    ((ushort4*)enc_bf)[i] = o;
  } else if (blk < 8320){                // eW: 32,768 f32x4
    int i = (blk - 8192) * 256 + tid;
    f32x4 v = ((const f32x4*)eW)[i];
    ushort4 o;
    o.x = f2bf(v[0]); o.y = f2bf(v[1]); o.z = f2bf(v[2]); o.w = f2bf(v[3]);
    ((ushort4*)encW_bf)[i] = o;
  } else {                               // dq [32][256] f32, hidden [32][512] bf16
    int t = (blk - 8320) * 256 + tid;
    if (t < S_ * AD_){
      int s = t >> 8, a = t & 255;
      const float* p = pos + s * ED_;
      const float* wrow = dW + a * ED_;
      float acc = db[a];
      #pragma unroll 4
      for (int e = 0; e < ED_; ++e) acc += p[e] * wrow[e];
      dq[t] = acc;
    } else if (t < S_ * AD_ + S_ * HD_){
      int u = t - S_ * AD_;
      int s = u >> 9, h = u & 511;
      const float* p = pos + s * ED_;
      const float* wrow = hW + h * ED_;
      float acc = hb[h];
      #pragma unroll 4
      for (int e = 0; e < ED_; ++e) acc += p[e] * wrow[e];
      hbf[u] = f2bf(acc);
    }
  }
}

// ---------------- enc_proj GEMM (128x128 tile, 2-phase dbuf, swizzled LDS):
//   [16384x512]bf16 @ [256x512]bf16^T -> bf16 + bias
extern "C" __global__ void __launch_bounds__(256, 4)
k_gemm_encp(const unsigned short* __restrict__ A, const unsigned short* __restrict__ Bt,
            const float* __restrict__ bias, unsigned short* __restrict__ C){
  __shared__ unsigned short As[2][128 * 32];
  __shared__ unsigned short Bs[2][128 * 32];
  int bm = blockIdx.x >> 1, bn = blockIdx.x & 1;
  int tid = threadIdx.x, wid = tid >> 6, lane = tid & 63;
  int fr = lane & 15, fq = lane >> 4;
  int wm = wid >> 1, wn = wid & 1;       // 2x2 waves; wave tile 64x64
  int srow = lane >> 2;
  int scol = ((lane & 3) ^ ((lane >> 3) & 3)) * 8;   // pre-swizzled source col
  int c0 = wid * 2;
  const unsigned short* aS0 = A  + (size_t)(bm * 128 + c0 * 16 + srow) * 512 + scol;
  const unsigned short* aS1 = aS0 + (size_t)16 * 512;
  const unsigned short* bS0 = Bt + (size_t)(bn * 128 + c0 * 16 + srow) * 512 + scol;
  const unsigned short* bS1 = bS0 + (size_t)16 * 512;
  int swzfq = (fq ^ ((fr >> 1) & 3)) * 8;

  f32x4 acc[4][4];
  #pragma unroll
  for (int i = 0; i < 4; ++i)
    #pragma unroll
    for (int j = 0; j < 4; ++j) acc[i][j] = (f32x4)0.0f;

#define STAGE_E(buf, kk) do { \
    gl_lds16(aS0 + (kk), &As[buf][c0 * 512]); \
    gl_lds16(aS1 + (kk), &As[buf][c0 * 512 + 512]); \
    gl_lds16(bS0 + (kk), &Bs[buf][c0 * 512]); \
    gl_lds16(bS1 + (kk), &Bs[buf][c0 * 512 + 512]); \
  } while (0)

  STAGE_E(0, 0);
  __syncthreads();

  int cur = 0;
  for (int t = 0; t < 16; ++t){
    if (t < 15) STAGE_E(cur ^ 1, (size_t)(t + 1) * 32);
    short8 a[4], b[4];
    #pragma unroll
    for (int mf = 0; mf < 4; ++mf) a[mf] = *(const short8*)&As[cur][(wm * 64 + mf * 16 + fr) * 32 + swzfq];
    #pragma unroll
    for (int nf = 0; nf < 4; ++nf) b[nf] = *(const short8*)&Bs[cur][(wn * 64 + nf * 16 + fr) * 32 + swzfq];
    #pragma unroll
    for (int mf = 0; mf < 4; ++mf)
      #pragma unroll
      for (int nf = 0; nf < 4; ++nf)
        acc[mf][nf] = __builtin_amdgcn_mfma_f32_16x16x32_bf16(a[mf], b[nf], acc[mf][nf], 0, 0, 0);
    __syncthreads();
    cur ^= 1;
  }
#undef STAGE_E

  #pragma unroll
  for (int mf = 0; mf < 4; ++mf){
    int row = bm * 128 + wm * 64 + mf * 16 + fq * 4;
    #pragma unroll
    for (int nf = 0; nf < 4; ++nf){
      int col = bn * 128 + wn * 64 + nf * 16 + fr;
      float bv = bias[col];
      #pragma unroll
      for (int j = 0; j < 4; ++j)
        C[(size_t)(row + j) * 256 + col] = f2bf(acc[mf][nf][j] + bv);
    }
  }
}

// ---------------- attention scores + softmax -> weights [B][S][L] f32 ----------------
extern "C" __global__ void __launch_bounds__(256)
k_attn(const unsigned short* __restrict__ encp, const float* __restrict__ dq,
       const float* __restrict__ vW, float* __restrict__ wgt){
  int idx = blockIdx.x;
  int wg = (idx & 7) * 128 + (idx >> 3);   // bijective: 1024 % 8 == 0
  int b = wg >> 5, s = wg & 31;
  int tid = threadIdx.x, wid = tid >> 6, lane = tid & 63;
  int half = lane >> 5, a0 = (lane & 31) * 8;
  __shared__ float sc[512];
  __shared__ float redm[4], reds[4];
  f32x4 dqa = *(const f32x4*)&dq[s * AD_ + a0];
  f32x4 dqb = *(const f32x4*)&dq[s * AD_ + a0 + 4];
  f32x4 va  = *(const f32x4*)&vW[a0];
  f32x4 vb  = *(const f32x4*)&vW[a0 + 4];
  for (int it = 0; it < 64; ++it){
    int l = wid * 128 + it * 2 + half;
    short8 e8 = *(const short8*)&encp[((size_t)(b * 512 + l)) * 256 + a0];
    float p = 0.0f;
    #pragma unroll
    for (int j = 0; j < 4; ++j) p += tanh_fast(bf2f((unsigned short)e8[j]) + dqa[j]) * va[j];
    #pragma unroll
    for (int j = 0; j < 4; ++j) p += tanh_fast(bf2f((unsigned short)e8[4 + j]) + dqb[j]) * vb[j];
    #pragma unroll
    for (int off = 16; off >= 1; off >>= 1) p += __shfl_xor(p, off);
    if ((lane & 31) == 0) sc[l] = p;
  }
  __syncthreads();
  float s0 = sc[tid], s1 = sc[tid + 256];
  float m = fmaxf(s0, s1);
  #pragma unroll
  for (int off = 32; off >= 1; off >>= 1) m = fmaxf(m, __shfl_xor(m, off));
  if (lane == 0) redm[wid] = m;
  __syncthreads();
  m = fmaxf(fmaxf(redm[0], redm[1]), fmaxf(redm[2], redm[3]));
  float e0 = __expf(s0 - m), e1 = __expf(s1 - m);
  float sum = e0 + e1;
  #pragma unroll
  for (int off = 32; off >= 1; off >>= 1) sum += __shfl_xor(sum, off);
  if (lane == 0) reds[wid] = sum;
  __syncthreads();
  float tot = reds[0] + reds[1] + reds[2] + reds[3];
  float inv = __builtin_amdgcn_rcpf(tot);
  size_t base = (size_t)(b * 32 + s) * 512;
  wgt[base + tid] = e0 * inv;
  wgt[base + tid + 256] = e1 * inv;
}

// ---------------- context: ctx[b*32+s][d] = sum_l w[b,s,l] * enc_bf[b,l,d] -> bf16 ----------
extern "C" __global__ void __launch_bounds__(256)
k_ctx(const unsigned short* __restrict__ encb, const float* __restrict__ wgt,
      unsigned short* __restrict__ ctx){
  int b = blockIdx.x >> 4, dt = blockIdx.x & 15;
  int tid = threadIdx.x;
  __shared__ float wl[32 * 512];
  #pragma unroll 8
  for (int i = 0; i < 64; ++i)
    wl[i * 256 + tid] = wgt[(size_t)b * 16384 + i * 256 + tid];
  __syncthreads();
  int d = dt * 32 + (tid & 31);
  int grp = tid >> 5;
  float acc0 = 0, acc1 = 0, acc2 = 0, acc3 = 0;
  const unsigned short* ebase = encb + (size_t)b * 262144 + d;   // 512*512
  const float* w0 = &wl[(grp * 4 + 0) * 512];
  const float* w1 = &wl[(grp * 4 + 1) * 512];
  const float* w2 = &wl[(grp * 4 + 2) * 512];
  const float* w3 = &wl[(grp * 4 + 3) * 512];
  #pragma unroll 8
  for (int l = 0; l < 512; ++l){
    float e = bf2f(ebase[(size_t)l * 512]);
    acc0 += w0[l] * e; acc1 += w1[l] * e; acc2 += w2[l] * e; acc3 += w3[l] * e;
  }
  size_t obase = (size_t)(b * 32 + grp * 4) * 512 + d;
  ctx[obase]        = f2bf(acc0);
  ctx[obase + 512]  = f2bf(acc1);
  ctx[obase + 1024] = f2bf(acc2);
  ctx[obase + 1536] = f2bf(acc3);
}

// ---------------- fused: Wc_bf convert (cols 512:1024) + logh (cols 0:512) ----------------
extern "C" __global__ void __launch_bounds__(256)
k_wprep(const float* __restrict__ fcW, const unsigned short* __restrict__ hbf,
        const float* __restrict__ fcb, unsigned short* __restrict__ Wc,
        float* __restrict__ logh){
  int bn = blockIdx.x;                       // 500 blocks x 64 rows of fcW
  int tid = threadIdx.x, wid = tid >> 6, lane = tid & 63;
  int fr = lane & 15, fq = lane >> 4;
  // part 1: convert upper half of 64 rows
  #pragma unroll 8
  for (int i = 0; i < 32; ++i){
    int idx = i * 256 + tid;                 // 8192 f32x4 = 64 rows x 512 cols
    int row = idx >> 7, c4 = idx & 127;
    f32x4 v = *(const f32x4*)&fcW[(size_t)(bn * 64 + row) * 1024 + 512 + c4 * 4];
    ushort4 o;
    o.x = f2bf(v[0]); o.y = f2bf(v[1]); o.z = f2bf(v[2]); o.w = f2bf(v[3]);
    *(ushort4*)&Wc[(size_t)(bn * 64 + row) * 512 + c4 * 4] = o;
  }
  // part 2: logh for these 64 cols (LDS-free, bf16 MFMA vs hbf)
  int col = bn * 64 + wid * 16 + fr;
  const float* brow = fcW + (size_t)col * 1024;
  f32x4 acc0 = (f32x4)0.0f, acc1 = (f32x4)0.0f;
  #pragma unroll 4
  for (int k0 = 0; k0 < 512; k0 += 32){
    int ko = k0 + fq * 8;
    f32x4 b0 = *(const f32x4*)(brow + ko);
    f32x4 b1 = *(const f32x4*)(brow + ko + 4);
    short8 bfr;
    bfr[0] = (short)f2bf(b0[0]); bfr[1] = (short)f2bf(b0[1]);
    bfr[2] = (short)f2bf(b0[2]); bfr[3] = (short)f2bf(b0[3]);
    bfr[4] = (short)f2bf(b1[0]); bfr[5] = (short)f2bf(b1[1]);
    bfr[6] = (short)f2bf(b1[2]); bfr[7] = (short)f2bf(b1[3]);
    short8 a0 = *(const short8*)&hbf[(size_t)fr * 512 + ko];
    short8 a1 = *(const short8*)&hbf[(size_t)(16 + fr) * 512 + ko];
    acc0 = __builtin_amdgcn_mfma_f32_16x16x32_bf16(a0, bfr, acc0, 0, 0, 0);
    acc1 = __builtin_amdgcn_mfma_f32_16x16x32_bf16(a1, bfr, acc1, 0, 0, 0);
  }
  float bv = fcb[col];
  #pragma unroll
  for (int j = 0; j < 4; ++j){
    logh[(size_t)(fq * 4 + j) * VOC_ + col]      = acc0[j] + bv;
    logh[(size_t)(16 + fq * 4 + j) * VOC_ + col] = acc1[j] + bv;
  }
}

// ---------------- main GEMM (128x256 tile, wave 64x64, A-dbuf + B-3buf, vmcnt(2)):
//   out[m][v] = ctx[m] . Wc[v] + logh[m&31][v]
//   1000 blocks, <=128 regs/wave -> 2 resident blocks/CU + oversubscription
extern "C" __global__ void __launch_bounds__(512, 4)
k_gemm_main(const unsigned short* __restrict__ Abf, const unsigned short* __restrict__ Wc,
            const float* __restrict__ logh, float* __restrict__ out){
  __shared__ unsigned short As[2][128 * 32];   // 16 KB: A double-buffer (ctx, L2-resident)
  __shared__ unsigned short Bs[3][256 * 32];   // 48 KB: B triple-buffer (Wc, HBM)
  // 1000 blocks; XCD swizzle (1000 % 8 == 0): 125 consecutive wg per XCD; bm inner
  // so the 8 bm-blocks sharing a B-panel are adjacent on one XCD.
  int orig = blockIdx.x;
  int wg = (orig & 7) * 125 + (orig >> 3);
  int bm = wg & 7, bn = wg >> 3;            // bm<8, bn<125
  int tid = threadIdx.x, wid = tid >> 6, lane = tid & 63;
  int fr = lane & 15, fq = lane >> 4;
  int wm = wid >> 2, wn = wid & 3;          // 2x4 waves; wave tile 64x64
  int abase = bm * 128, bbase = bn * 256;
  // staging: lane l writes LDS byte l*16 within its wave's 16-row chunk (linear).
  // XOR-swizzle p(r)=(r>>1)&3 via pre-swizzled GLOBAL source col (R4/R5: 0 conflicts).
  int srow = lane >> 2;
  int scol = ((lane & 3) ^ ((lane >> 3) & 3)) * 8;
  const unsigned short* aS0 = Abf + (size_t)(abase + wid * 16 + srow) * 512 + scol;
  const unsigned short* bS0 = Wc  + (size_t)(bbase + wid * 32 + srow) * 512 + scol;
  const unsigned short* bS1 = bS0 + (size_t)16 * 512;
  int swzfq = (fq ^ ((fr >> 1) & 3)) * 8;

  f32x4 acc[4][4];
  #pragma unroll
  for (int i = 0; i < 4; ++i)
    #pragma unroll
    for (int jj = 0; jj < 4; ++jj) acc[i][jj] = (f32x4)0.0f;

#define STAGE_A(buf, kk) gl_lds16(aS0 + (kk), &As[buf][wid * 512])
#define STAGE_B(buf, kk) do { \
    gl_lds16(bS0 + (kk), &Bs[buf][wid * 1024]); \
    gl_lds16(bS1 + (kk), &Bs[buf][wid * 1024 + 512]); \
  } while (0)

  // prologue: A(0), B(0) needed now; B(1) may stay in flight.
  STAGE_A(0, 0);
  STAGE_B(0, 0);
  STAGE_B(1, 32);
  asm volatile("s_waitcnt vmcnt(2)" ::: "memory");   // A0,B0 landed; B1 flying
  __builtin_amdgcn_s_barrier();
  __builtin_amdgcn_sched_barrier(0);

  #pragma unroll
  for (int t = 0; t < 16; ++t){
    const int ca = t & 1, cb = t % 3;
    short8 a[4], b[4];
    // ---- phase 0: stage A(t+1); compute mf0-1 ----
    if (t < 15) STAGE_A(ca ^ 1, (size_t)(t + 1) * 32);
    #pragma unroll
    for (int nf = 0; nf < 4; ++nf)
      b[nf] = *(const short8*)&Bs[cb][(wn * 64 + nf * 16 + fr) * 32 + swzfq];
    #pragma unroll
    for (int mf = 0; mf < 2; ++mf)
      a[mf] = *(const short8*)&As[ca][(wm * 64 + mf * 16 + fr) * 32 + swzfq];
    __builtin_amdgcn_s_setprio(1);
    #pragma unroll
    for (int mf = 0; mf < 2; ++mf)
      #pragma unroll
      for (int nf = 0; nf < 4; ++nf)
        acc[mf][nf] = __builtin_amdgcn_mfma_f32_16x16x32_bf16(a[mf], b[nf], acc[mf][nf], 0, 0, 0);
    __builtin_amdgcn_s_setprio(0);
    // ---- phase 1: stage B(t+2); compute mf2-3 ----
    if (t < 14) STAGE_B((t + 2) % 3, (size_t)(t + 2) * 32);
    #pragma unroll
    for (int mf = 2; mf < 4; ++mf)
      a[mf] = *(const short8*)&As[ca][(wm * 64 + mf * 16 + fr) * 32 + swzfq];
    __builtin_amdgcn_s_setprio(1);
    #pragma unroll
    for (int mf = 2; mf < 4; ++mf)
      #pragma unroll
      for (int nf = 0; nf < 4; ++nf)
        acc[mf][nf] = __builtin_amdgcn_mfma_f32_16x16x32_bf16(a[mf], b[nf], acc[mf][nf], 0, 0, 0);
    __builtin_amdgcn_s_setprio(0);
    // ---- tile boundary: A(t+1),B(t+1) landed; B(t+2) may fly ----
    if (t < 14)       asm volatile("s_waitcnt vmcnt(2)" ::: "memory");
    else if (t == 14) asm volatile("s_waitcnt vmcnt(0)" ::: "memory");
    if (t < 15){
      __builtin_amdgcn_s_barrier();
      __builtin_amdgcn_sched_barrier(0);
    }
  }
#undef STAGE_A
#undef STAGE_B

  #pragma unroll
  for (int mf = 0; mf < 4; ++mf){
    int rowb = bm * 128 + wm * 64 + mf * 16 + fq * 4;
    #pragma unroll
    for (int nf = 0; nf < 4; ++nf){
      int col = bn * 256 + wn * 64 + nf * 16 + fr;
      #pragma unroll
      for (int jj = 0; jj < 4; ++jj){
        int r = rowb + jj;
        out[(size_t)r * VOC_ + col] = acc[mf][nf][jj] + logh[(size_t)(r & 31) * VOC_ + col];
      }
    }
  }
}

extern "C" void kernel_launch(void* const* d_in, const int* in_sizes, int n_in,
                              void* d_out, int out_size, void* d_ws, size_t ws_size,
                              hipStream_t stream){
  const float* enc = (const float*)d_in[0];
  // d_in[1] = target_seq (unused: only its shape matters in the reference)
  const float* pos = (const float*)d_in[2];
  const float* dW  = (const float*)d_in[3];
  const float* db  = (const float*)d_in[4];
  const float* eW  = (const float*)d_in[5];
  const float* eb  = (const float*)d_in[6];
  const float* vW  = (const float*)d_in[7];
  // d_in[8] = attn_score_b: constant over l, cancels exactly in softmax
  const float* hW  = (const float*)d_in[9];
  const float* hb  = (const float*)d_in[10];
  const float* fcW = (const float*)d_in[11];
  const float* fcb = (const float*)d_in[12];
  float* out = (float*)d_out;

  char* w = (char*)d_ws;
  unsigned short* Wc_bf   = (unsigned short*)(w);               // 32,768,000 B
  unsigned short* enc_bf  = (unsigned short*)(w + 32768000);    // 16,777,216 B
  unsigned short* encp_bf = (unsigned short*)(w + 49545216);    //  8,388,608 B
  unsigned short* ctx     = (unsigned short*)(w + 57933824);    //  1,048,576 B
  float*          logh    = (float*)(w + 58982400);             //  4,096,000 B
  float*          dq      = (float*)(w + 63078400);             //     32,768 B
  unsigned short* hbf     = (unsigned short*)(w + 63111168);    //     32,768 B
  unsigned short* encW_bf = (unsigned short*)(w + 63143936);    //    262,144 B
  float*          wgt     = (float*)(w + 63406080);             //  2,097,152 B (total ~65.5 MB)

  k_prep<<<dim3(8416), dim3(256), 0, stream>>>(enc, enc_bf, eW, encW_bf,
                                               pos, dW, db, hW, hb, dq, hbf);
  k_gemm_encp<<<dim3(256), dim3(256), 0, stream>>>(enc_bf, encW_bf, eb, encp_bf);
  k_attn<<<dim3(1024), dim3(256), 0, stream>>>(encp_bf, dq, vW, wgt);
  k_ctx<<<dim3(512), dim3(256), 0, stream>>>(enc_bf, wgt, ctx);
  k_wprep<<<dim3(500), dim3(256), 0, stream>>>(fcW, hbf, fcb, Wc_bf, logh);
  k_gemm_main<<<dim3(1000), dim3(512), 0, stream>>>(ctx, Wc_bf, logh, out);
}

// Round 8
// 204.519 us; speedup vs baseline: 1.1658x; 1.0233x over previous
//
#include <hip/hip_runtime.h>
#include <hip/hip_bf16.h>
#include <stdint.h>

typedef __attribute__((ext_vector_type(4))) float f32x4;
typedef __attribute__((ext_vector_type(8))) short short8;

#define B_   32
#define L_   512
#define DE_  512
#define S_   32
#define ED_  128
#define AD_  256
#define HD_  512
#define VOC_ 32000
#define M_   1024

__device__ __forceinline__ unsigned short f2bf(float f){
  union { float f; unsigned int u; } v; v.f = f;
  unsigned int u = v.u;
  unsigned int r = (u + 0x7FFFu + ((u >> 16) & 1u)) >> 16;  // RNE
  return (unsigned short)r;
}

__device__ __forceinline__ float bf2f(unsigned short u){
  union { unsigned int u; float f; } v; v.u = ((unsigned int)u) << 16;
  return v.f;
}

__device__ __forceinline__ float tanh_fast(float x){
  float t = __expf(2.0f * x);
  return (t - 1.0f) * __builtin_amdgcn_rcpf(t + 1.0f);
}

__device__ __forceinline__ void gl_lds16(const void* g, void* l){
  __builtin_amdgcn_global_load_lds(
      (const __attribute__((address_space(1))) unsigned int*)g,
      (__attribute__((address_space(3))) unsigned int*)l, 16, 0, 0);
}

// ---------------- fused prologue: enc cvt (8192 blk) + eW cvt (128 blk) + small (96 blk) ----
extern "C" __global__ void __launch_bounds__(256)
k_prep(const float* __restrict__ enc, unsigned short* __restrict__ enc_bf,
       const float* __restrict__ eW, unsigned short* __restrict__ encW_bf,
       const float* __restrict__ pos,
       const float* __restrict__ dW, const float* __restrict__ db,
       const float* __restrict__ hW, const float* __restrict__ hb,
       float* __restrict__ dq, unsigned short* __restrict__ hbf){
  int blk = blockIdx.x, tid = threadIdx.x;
  if (blk < 8192){                       // enc: 2,097,152 f32x4, one per thread
    int i = blk * 256 + tid;
    f32x4 v = ((const f32x4*)enc)[i];
    ushort4 o;
    o.x = f2bf(v[0]); o.y = f2bf(v[1]); o.z = f2bf(v[2]); o.w = f2bf(v[3]);
    ((ushort4*)enc_bf)[i] = o;
  } else if (blk < 8320){                // eW: 32,768 f32x4
    int i = (blk - 8192) * 256 + tid;
    f32x4 v = ((const f32x4*)eW)[i];
    ushort4 o;
    o.x = f2bf(v[0]); o.y = f2bf(v[1]); o.z = f2bf(v[2]); o.w = f2bf(v[3]);
    ((ushort4*)encW_bf)[i] = o;
  } else {                               // dq [32][256] f32, hidden [32][512] bf16
    int t = (blk - 8320) * 256 + tid;
    if (t < S_ * AD_){
      int s = t >> 8, a = t & 255;
      const float* p = pos + s * ED_;
      const float* wrow = dW + a * ED_;
      float acc = db[a];
      #pragma unroll 4
      for (int e = 0; e < ED_; ++e) acc += p[e] * wrow[e];
      dq[t] = acc;
    } else if (t < S_ * AD_ + S_ * HD_){
      int u = t - S_ * AD_;
      int s = u >> 9, h = u & 511;
      const float* p = pos + s * ED_;
      const float* wrow = hW + h * ED_;
      float acc = hb[h];
      #pragma unroll 4
      for (int e = 0; e < ED_; ++e) acc += p[e] * wrow[e];
      hbf[u] = f2bf(acc);
    }
  }
}

// ---------------- enc_proj GEMM (128x128 tile, 2-phase dbuf, swizzled LDS):
//   [16384x512]bf16 @ [256x512]bf16^T -> bf16 + bias
extern "C" __global__ void __launch_bounds__(256, 4)
k_gemm_encp(const unsigned short* __restrict__ A, const unsigned short* __restrict__ Bt,
            const float* __restrict__ bias, unsigned short* __restrict__ C){
  __shared__ unsigned short As[2][128 * 32];
  __shared__ unsigned short Bs[2][128 * 32];
  int bm = blockIdx.x >> 1, bn = blockIdx.x & 1;
  int tid = threadIdx.x, wid = tid >> 6, lane = tid & 63;
  int fr = lane & 15, fq = lane >> 4;
  int wm = wid >> 1, wn = wid & 1;       // 2x2 waves; wave tile 64x64
  int srow = lane >> 2;
  int scol = ((lane & 3) ^ ((lane >> 3) & 3)) * 8;   // pre-swizzled source col
  int c0 = wid * 2;
  const unsigned short* aS0 = A  + (size_t)(bm * 128 + c0 * 16 + srow) * 512 + scol;
  const unsigned short* aS1 = aS0 + (size_t)16 * 512;
  const unsigned short* bS0 = Bt + (size_t)(bn * 128 + c0 * 16 + srow) * 512 + scol;
  const unsigned short* bS1 = bS0 + (size_t)16 * 512;
  int swzfq = (fq ^ ((fr >> 1) & 3)) * 8;

  f32x4 acc[4][4];
  #pragma unroll
  for (int i = 0; i < 4; ++i)
    #pragma unroll
    for (int j = 0; j < 4; ++j) acc[i][j] = (f32x4)0.0f;

#define STAGE_E(buf, kk) do { \
    gl_lds16(aS0 + (kk), &As[buf][c0 * 512]); \
    gl_lds16(aS1 + (kk), &As[buf][c0 * 512 + 512]); \
    gl_lds16(bS0 + (kk), &Bs[buf][c0 * 512]); \
    gl_lds16(bS1 + (kk), &Bs[buf][c0 * 512 + 512]); \
  } while (0)

  STAGE_E(0, 0);
  __syncthreads();

  int cur = 0;
  for (int t = 0; t < 16; ++t){
    if (t < 15) STAGE_E(cur ^ 1, (size_t)(t + 1) * 32);
    short8 a[4], b[4];
    #pragma unroll
    for (int mf = 0; mf < 4; ++mf) a[mf] = *(const short8*)&As[cur][(wm * 64 + mf * 16 + fr) * 32 + swzfq];
    #pragma unroll
    for (int nf = 0; nf < 4; ++nf) b[nf] = *(const short8*)&Bs[cur][(wn * 64 + nf * 16 + fr) * 32 + swzfq];
    #pragma unroll
    for (int mf = 0; mf < 4; ++mf)
      #pragma unroll
      for (int nf = 0; nf < 4; ++nf)
        acc[mf][nf] = __builtin_amdgcn_mfma_f32_16x16x32_bf16(a[mf], b[nf], acc[mf][nf], 0, 0, 0);
    __syncthreads();
    cur ^= 1;
  }
#undef STAGE_E

  #pragma unroll
  for (int mf = 0; mf < 4; ++mf){
    int row = bm * 128 + wm * 64 + mf * 16 + fq * 4;
    #pragma unroll
    for (int nf = 0; nf < 4; ++nf){
      int col = bn * 128 + wn * 64 + nf * 16 + fr;
      float bv = bias[col];
      #pragma unroll
      for (int j = 0; j < 4; ++j)
        C[(size_t)(row + j) * 256 + col] = f2bf(acc[mf][nf][j] + bv);
    }
  }
}

// ---------------- fused middle: wprep (blocks 0-499) || attn (blocks 500-1523) ----------
// wprep: HBM-bound (streams 131 MB fcW); attn: VALU-bound (134M tanh).
// Co-scheduling hides the VALU work under the HBM stream.
extern "C" __global__ void __launch_bounds__(256)
k_mid(const float* __restrict__ fcW, const unsigned short* __restrict__ hbf,
      const float* __restrict__ fcb, unsigned short* __restrict__ Wc,
      float* __restrict__ logh,
      const unsigned short* __restrict__ encp, const float* __restrict__ dq,
      const float* __restrict__ vW, float* __restrict__ wgt){
  int blk = blockIdx.x;
  if (blk < 500){
    // ---------------- wprep: Wc_bf convert (cols 512:1024) + logh (cols 0:512) --------
    int bn = blk;
    int tid = threadIdx.x, wid = tid >> 6, lane = tid & 63;
    int fr = lane & 15, fq = lane >> 4;
    #pragma unroll 8
    for (int i = 0; i < 32; ++i){
      int idx = i * 256 + tid;                 // 8192 f32x4 = 64 rows x 512 cols
      int row = idx >> 7, c4 = idx & 127;
      f32x4 v = *(const f32x4*)&fcW[(size_t)(bn * 64 + row) * 1024 + 512 + c4 * 4];
      ushort4 o;
      o.x = f2bf(v[0]); o.y = f2bf(v[1]); o.z = f2bf(v[2]); o.w = f2bf(v[3]);
      *(ushort4*)&Wc[(size_t)(bn * 64 + row) * 512 + c4 * 4] = o;
    }
    int col = bn * 64 + wid * 16 + fr;
    const float* brow = fcW + (size_t)col * 1024;
    f32x4 acc0 = (f32x4)0.0f, acc1 = (f32x4)0.0f;
    #pragma unroll 4
    for (int k0 = 0; k0 < 512; k0 += 32){
      int ko = k0 + fq * 8;
      f32x4 b0 = *(const f32x4*)(brow + ko);
      f32x4 b1 = *(const f32x4*)(brow + ko + 4);
      short8 bfr;
      bfr[0] = (short)f2bf(b0[0]); bfr[1] = (short)f2bf(b0[1]);
      bfr[2] = (short)f2bf(b0[2]); bfr[3] = (short)f2bf(b0[3]);
      bfr[4] = (short)f2bf(b1[0]); bfr[5] = (short)f2bf(b1[1]);
      bfr[6] = (short)f2bf(b1[2]); bfr[7] = (short)f2bf(b1[3]);
      short8 a0 = *(const short8*)&hbf[(size_t)fr * 512 + ko];
      short8 a1 = *(const short8*)&hbf[(size_t)(16 + fr) * 512 + ko];
      acc0 = __builtin_amdgcn_mfma_f32_16x16x32_bf16(a0, bfr, acc0, 0, 0, 0);
      acc1 = __builtin_amdgcn_mfma_f32_16x16x32_bf16(a1, bfr, acc1, 0, 0, 0);
    }
    float bv = fcb[col];
    #pragma unroll
    for (int j = 0; j < 4; ++j){
      logh[(size_t)(fq * 4 + j) * VOC_ + col]      = acc0[j] + bv;
      logh[(size_t)(16 + fq * 4 + j) * VOC_ + col] = acc1[j] + bv;
    }
  } else {
    // ---------------- attn: scores + softmax -> weights [B][S][L] f32 ----------------
    int wg = blk - 500;                      // 1024 blocks: b = wg>>5, s = wg&31
    int b = wg >> 5, s = wg & 31;
    int tid = threadIdx.x, wid = tid >> 6, lane = tid & 63;
    int half = lane >> 5, a0 = (lane & 31) * 8;
    __shared__ float sc[512];
    __shared__ float redm[4], reds[4];
    f32x4 dqa = *(const f32x4*)&dq[s * AD_ + a0];
    f32x4 dqb = *(const f32x4*)&dq[s * AD_ + a0 + 4];
    f32x4 va  = *(const f32x4*)&vW[a0];
    f32x4 vb  = *(const f32x4*)&vW[a0 + 4];
    for (int it = 0; it < 64; ++it){
      int l = wid * 128 + it * 2 + half;
      short8 e8 = *(const short8*)&encp[((size_t)(b * 512 + l)) * 256 + a0];
      float p = 0.0f;
      #pragma unroll
      for (int j = 0; j < 4; ++j) p += tanh_fast(bf2f((unsigned short)e8[j]) + dqa[j]) * va[j];
      #pragma unroll
      for (int j = 0; j < 4; ++j) p += tanh_fast(bf2f((unsigned short)e8[4 + j]) + dqb[j]) * vb[j];
      #pragma unroll
      for (int off = 16; off >= 1; off >>= 1) p += __shfl_xor(p, off);
      if ((lane & 31) == 0) sc[l] = p;
    }
    __syncthreads();
    float s0 = sc[tid], s1 = sc[tid + 256];
    float m = fmaxf(s0, s1);
    #pragma unroll
    for (int off = 32; off >= 1; off >>= 1) m = fmaxf(m, __shfl_xor(m, off));
    if (lane == 0) redm[wid] = m;
    __syncthreads();
    m = fmaxf(fmaxf(redm[0], redm[1]), fmaxf(redm[2], redm[3]));
    float e0 = __expf(s0 - m), e1 = __expf(s1 - m);
    float sum = e0 + e1;
    #pragma unroll
    for (int off = 32; off >= 1; off >>= 1) sum += __shfl_xor(sum, off);
    if (lane == 0) reds[wid] = sum;
    __syncthreads();
    float tot = reds[0] + reds[1] + reds[2] + reds[3];
    float inv = __builtin_amdgcn_rcpf(tot);
    size_t base = (size_t)(b * 32 + s) * 512;
    wgt[base + tid] = e0 * inv;
    wgt[base + tid + 256] = e1 * inv;
  }
}

// ---------------- context: ctx[b*32+s][d] = sum_l w[b,s,l] * enc_bf[b,l,d] -> bf16 ----------
extern "C" __global__ void __launch_bounds__(256)
k_ctx(const unsigned short* __restrict__ encb, const float* __restrict__ wgt,
      unsigned short* __restrict__ ctx){
  int b = blockIdx.x >> 4, dt = blockIdx.x & 15;
  int tid = threadIdx.x;
  __shared__ float wl[32 * 512];
  #pragma unroll 8
  for (int i = 0; i < 64; ++i)
    wl[i * 256 + tid] = wgt[(size_t)b * 16384 + i * 256 + tid];
  __syncthreads();
  int d = dt * 32 + (tid & 31);
  int grp = tid >> 5;
  float acc0 = 0, acc1 = 0, acc2 = 0, acc3 = 0;
  const unsigned short* ebase = encb + (size_t)b * 262144 + d;   // 512*512
  const float* w0 = &wl[(grp * 4 + 0) * 512];
  const float* w1 = &wl[(grp * 4 + 1) * 512];
  const float* w2 = &wl[(grp * 4 + 2) * 512];
  const float* w3 = &wl[(grp * 4 + 3) * 512];
  #pragma unroll 8
  for (int l = 0; l < 512; ++l){
    float e = bf2f(ebase[(size_t)l * 512]);
    acc0 += w0[l] * e; acc1 += w1[l] * e; acc2 += w2[l] * e; acc3 += w3[l] * e;
  }
  size_t obase = (size_t)(b * 32 + grp * 4) * 512 + d;
  ctx[obase]        = f2bf(acc0);
  ctx[obase + 512]  = f2bf(acc1);
  ctx[obase + 1024] = f2bf(acc2);
  ctx[obase + 1536] = f2bf(acc3);
}

// ---------------- main GEMM (128x256 tile, wave 64x64, A-dbuf + B-3buf, vmcnt(2)):
//   out[m][v] = ctx[m] . Wc[v] + logh[m&31][v]
extern "C" __global__ void __launch_bounds__(512, 4)
k_gemm_main(const unsigned short* __restrict__ Abf, const unsigned short* __restrict__ Wc,
            const float* __restrict__ logh, float* __restrict__ out){
  __shared__ unsigned short As[2][128 * 32];   // 16 KB: A double-buffer (ctx, L2-resident)
  __shared__ unsigned short Bs[3][256 * 32];   // 48 KB: B triple-buffer (Wc, HBM)
  int orig = blockIdx.x;
  int wg = (orig & 7) * 125 + (orig >> 3);
  int bm = wg & 7, bn = wg >> 3;            // bm<8, bn<125
  int tid = threadIdx.x, wid = tid >> 6, lane = tid & 63;
  int fr = lane & 15, fq = lane >> 4;
  int wm = wid >> 2, wn = wid & 3;          // 2x4 waves; wave tile 64x64
  int abase = bm * 128, bbase = bn * 256;
  int srow = lane >> 2;
  int scol = ((lane & 3) ^ ((lane >> 3) & 3)) * 8;
  const unsigned short* aS0 = Abf + (size_t)(abase + wid * 16 + srow) * 512 + scol;
  const unsigned short* bS0 = Wc  + (size_t)(bbase + wid * 32 + srow) * 512 + scol;
  const unsigned short* bS1 = bS0 + (size_t)16 * 512;
  int swzfq = (fq ^ ((fr >> 1) & 3)) * 8;

  f32x4 acc[4][4];
  #pragma unroll
  for (int i = 0; i < 4; ++i)
    #pragma unroll
    for (int jj = 0; jj < 4; ++jj) acc[i][jj] = (f32x4)0.0f;

#define STAGE_A(buf, kk) gl_lds16(aS0 + (kk), &As[buf][wid * 512])
#define STAGE_B(buf, kk) do { \
    gl_lds16(bS0 + (kk), &Bs[buf][wid * 1024]); \
    gl_lds16(bS1 + (kk), &Bs[buf][wid * 1024 + 512]); \
  } while (0)

  STAGE_A(0, 0);
  STAGE_B(0, 0);
  STAGE_B(1, 32);
  asm volatile("s_waitcnt vmcnt(2)" ::: "memory");   // A0,B0 landed; B1 flying
  __builtin_amdgcn_s_barrier();
  __builtin_amdgcn_sched_barrier(0);

  #pragma unroll
  for (int t = 0; t < 16; ++t){
    const int ca = t & 1, cb = t % 3;
    short8 a[4], b[4];
    if (t < 15) STAGE_A(ca ^ 1, (size_t)(t + 1) * 32);
    #pragma unroll
    for (int nf = 0; nf < 4; ++nf)
      b[nf] = *(const short8*)&Bs[cb][(wn * 64 + nf * 16 + fr) * 32 + swzfq];
    #pragma unroll
    for (int mf = 0; mf < 2; ++mf)
      a[mf] = *(const short8*)&As[ca][(wm * 64 + mf * 16 + fr) * 32 + swzfq];
    __builtin_amdgcn_s_setprio(1);
    #pragma unroll
    for (int mf = 0; mf < 2; ++mf)
      #pragma unroll
      for (int nf = 0; nf < 4; ++nf)
        acc[mf][nf] = __builtin_amdgcn_mfma_f32_16x16x32_bf16(a[mf], b[nf], acc[mf][nf], 0, 0, 0);
    __builtin_amdgcn_s_setprio(0);
    if (t < 14) STAGE_B((t + 2) % 3, (size_t)(t + 2) * 32);
    #pragma unroll
    for (int mf = 2; mf < 4; ++mf)
      a[mf] = *(const short8*)&As[ca][(wm * 64 + mf * 16 + fr) * 32 + swzfq];
    __builtin_amdgcn_s_setprio(1);
    #pragma unroll
    for (int mf = 2; mf < 4; ++mf)
      #pragma unroll
      for (int nf = 0; nf < 4; ++nf)
        acc[mf][nf] = __builtin_amdgcn_mfma_f32_16x16x32_bf16(a[mf], b[nf], acc[mf][nf], 0, 0, 0);
    __builtin_amdgcn_s_setprio(0);
    if (t < 14)       asm volatile("s_waitcnt vmcnt(2)" ::: "memory");
    else if (t == 14) asm volatile("s_waitcnt vmcnt(0)" ::: "memory");
    if (t < 15){
      __builtin_amdgcn_s_barrier();
      __builtin_amdgcn_sched_barrier(0);
    }
  }
#undef STAGE_A
#undef STAGE_B

  #pragma unroll
  for (int mf = 0; mf < 4; ++mf){
    int rowb = bm * 128 + wm * 64 + mf * 16 + fq * 4;
    #pragma unroll
    for (int nf = 0; nf < 4; ++nf){
      int col = bn * 256 + wn * 64 + nf * 16 + fr;
      #pragma unroll
      for (int jj = 0; jj < 4; ++jj){
        int r = rowb + jj;
        out[(size_t)r * VOC_ + col] = acc[mf][nf][jj] + logh[(size_t)(r & 31) * VOC_ + col];
      }
    }
  }
}

extern "C" void kernel_launch(void* const* d_in, const int* in_sizes, int n_in,
                              void* d_out, int out_size, void* d_ws, size_t ws_size,
                              hipStream_t stream){
  const float* enc = (const float*)d_in[0];
  // d_in[1] = target_seq (unused: only its shape matters in the reference)
  const float* pos = (const float*)d_in[2];
  const float* dW  = (const float*)d_in[3];
  const float* db  = (const float*)d_in[4];
  const float* eW  = (const float*)d_in[5];
  const float* eb  = (const float*)d_in[6];
  const float* vW  = (const float*)d_in[7];
  // d_in[8] = attn_score_b: constant over l, cancels exactly in softmax
  const float* hW  = (const float*)d_in[9];
  const float* hb  = (const float*)d_in[10];
  const float* fcW = (const float*)d_in[11];
  const float* fcb = (const float*)d_in[12];
  float* out = (float*)d_out;

  char* w = (char*)d_ws;
  unsigned short* Wc_bf   = (unsigned short*)(w);               // 32,768,000 B
  unsigned short* enc_bf  = (unsigned short*)(w + 32768000);    // 16,777,216 B
  unsigned short* encp_bf = (unsigned short*)(w + 49545216);    //  8,388,608 B
  unsigned short* ctx     = (unsigned short*)(w + 57933824);    //  1,048,576 B
  float*          logh    = (float*)(w + 58982400);             //  4,096,000 B
  float*          dq      = (float*)(w + 63078400);             //     32,768 B
  unsigned short* hbf     = (unsigned short*)(w + 63111168);    //     32,768 B
  unsigned short* encW_bf = (unsigned short*)(w + 63143936);    //    262,144 B
  float*          wgt     = (float*)(w + 63406080);             //  2,097,152 B (total ~65.5 MB)

  k_prep<<<dim3(8416), dim3(256), 0, stream>>>(enc, enc_bf, eW, encW_bf,
                                               pos, dW, db, hW, hb, dq, hbf);
  k_gemm_encp<<<dim3(256), dim3(256), 0, stream>>>(enc_bf, encW_bf, eb, encp_bf);
  k_mid<<<dim3(1524), dim3(256), 0, stream>>>(fcW, hbf, fcb, Wc_bf, logh,
                                              encp_bf, dq, vW, wgt);
  k_ctx<<<dim3(512), dim3(256), 0, stream>>>(enc_bf, wgt, ctx);
  k_gemm_main<<<dim3(1000), dim3(512), 0, stream>>>(ctx, Wc_bf, logh, out);
}